// Round 2
// baseline (5327.971 us; speedup 1.0000x reference)
//
#include <hip/hip_runtime.h>
#include <math.h>

#define NN 500
#define DD 64
#define ADJ_LD 512
#define BS_TOT 1024          // B*S
#define I_DIM 32000          // N*D
#define KC 20                // K chunks for GRU pre-GEMM
#define KCH 1600             // 32000/20

__device__ __forceinline__ float gelu_f(float x) {
    return 0.5f * x * (1.0f + erff(x * 0.70710678118654752440f));
}

// ---------------------------------------------------------------- adjacency
// adjT[m*512 + n] = adj[n][m], adj[n][m] = softmax over m of (from[n]·to[m] / 0.5)
__global__ __launch_bounds__(512)
void adj_kernel(const float* __restrict__ fe, const float* __restrict__ te,
                float* __restrict__ adjT)
{
    __shared__ float fr[32];
    __shared__ float red[8];
    __shared__ float red2[8];
    const int n = blockIdx.x;
    const int tid = threadIdx.x;
    if (tid < 32) fr[tid] = fe[n * 32 + tid];
    __syncthreads();
    const int m = tid;
    float s = -1e30f;
    if (m < NN) {
        float acc = 0.f;
        #pragma unroll
        for (int f = 0; f < 32; ++f) acc += fr[f] * te[m * 32 + f];
        s = acc * 2.0f;   // 1/TEMP
    }
    float v = s;
    #pragma unroll
    for (int off = 32; off; off >>= 1) v = fmaxf(v, __shfl_xor(v, off));
    if ((tid & 63) == 0) red[tid >> 6] = v;
    __syncthreads();
    float bmax = red[0];
    #pragma unroll
    for (int i = 1; i < 8; ++i) bmax = fmaxf(bmax, red[i]);
    float e = (m < NN) ? expf(s - bmax) : 0.f;
    float v2 = e;
    #pragma unroll
    for (int off = 32; off; off >>= 1) v2 += __shfl_xor(v2, off);
    if ((tid & 63) == 0) red2[tid >> 6] = v2;
    __syncthreads();
    float bsum = 0.f;
    #pragma unroll
    for (int i = 0; i < 8; ++i) bsum += red2[i];
    if (m < NN) adjT[(size_t)m * ADJ_LD + n] = e / bsum;
}

// ---------------------------------------------------------------- input proj
__global__ __launch_bounds__(256)
void proj_kernel(const float* __restrict__ xin, const float* __restrict__ ipW,
                 const float* __restrict__ ipb, float* __restrict__ X)
{
    __shared__ float wT[32 * 64];   // [f][d]
    __shared__ float xrow[4 * 32];
    const int tid = threadIdx.x;
    const int bs = blockIdx.y;
    const int n0 = blockIdx.x * 4;
    for (int idx = tid; idx < 2048; idx += 256) {
        int d = idx >> 5, f = idx & 31;
        wT[f * 64 + d] = ipW[idx];
    }
    if (tid < 128) xrow[tid] = xin[((size_t)bs * NN + n0) * 32 + tid];
    __syncthreads();
    const int nl = tid >> 6, lane = tid & 63;
    float acc = ipb[lane];
    #pragma unroll
    for (int f = 0; f < 32; ++f) acc += xrow[nl * 32 + f] * wT[f * 64 + lane];
    X[((size_t)bs * NN + n0 + nl) * DD + lane] = gelu_f(acc);
}

// ---------------------------------------------------------------- graph layer
// per (b,s) block, in-place on X. 8 waves x 8 m-rows/pass, 8 passes.
__global__ __launch_bounds__(512)
void graph_layer_kernel(float* __restrict__ X, const float* __restrict__ adjT,
                        const float* __restrict__ glW, const float* __restrict__ glb,
                        const float* __restrict__ glg, const float* __restrict__ glbe)
{
    extern __shared__ float smem[];
    float* xs  = smem;              // [500][64]
    float* tst = smem + NN * DD;    // [8 waves][4][64]
    float* bB  = tst + 8 * 4 * 64;  // 64
    float* bG  = bB + 64;
    float* bE  = bG + 64;

    const int tid  = threadIdx.x;
    const int lane = tid & 63;
    const int w    = tid >> 6;
    const int bs   = blockIdx.x;
    float* Xblk = X + (size_t)bs * NN * DD;

    // W column for this lane: wcol[d] = glW[e=lane][d]
    float wcol[64];
    #pragma unroll
    for (int d4 = 0; d4 < 16; ++d4) {
        float4 v = *(const float4*)&glW[lane * 64 + d4 * 4];
        wcol[d4 * 4 + 0] = v.x; wcol[d4 * 4 + 1] = v.y;
        wcol[d4 * 4 + 2] = v.z; wcol[d4 * 4 + 3] = v.w;
    }
    if (tid < 64) { bB[tid] = glb[tid]; bG[tid] = glg[tid]; bE[tid] = glbe[tid]; }
    {
        const float4* Xg4 = (const float4*)Xblk;
        float4* xs4 = (float4*)xs;
        for (int idx = tid; idx < NN * DD / 4; idx += 512) xs4[idx] = Xg4[idx];
    }
    __syncthreads();

    for (int p = 0; p < 8; ++p) {
        const int mb = __builtin_amdgcn_readfirstlane(p * 64 + w * 8);
        const float* arow[8];
        #pragma unroll
        for (int j = 0; j < 8; ++j) {
            int m = mb + j; if (m > NN - 1) m = NN - 1;
            arow[j] = adjT + (size_t)m * ADJ_LD;
        }
        float acc[8];
        #pragma unroll
        for (int j = 0; j < 8; ++j) acc[j] = 0.f;

        for (int n4 = 0; n4 < 125; ++n4) {
            float4 av[8];
            #pragma unroll
            for (int j = 0; j < 8; ++j) av[j] = *(const float4*)(arow[j] + n4 * 4);
            float xv0 = xs[(n4 * 4 + 0) * 64 + lane];
            float xv1 = xs[(n4 * 4 + 1) * 64 + lane];
            float xv2 = xs[(n4 * 4 + 2) * 64 + lane];
            float xv3 = xs[(n4 * 4 + 3) * 64 + lane];
            #pragma unroll
            for (int j = 0; j < 8; ++j)
                acc[j] += xv0 * av[j].x + xv1 * av[j].y + xv2 * av[j].z + xv3 * av[j].w;
        }

        float* tw = tst + w * 256;      // [4][64]
        for (int half = 0; half < 2; ++half) {
            #pragma unroll
            for (int jj = 0; jj < 4; ++jj) {
                int j = half * 4 + jj;
                int m = mb + j;
                float t = (m < NN) ? (xs[m * 64 + lane] + acc[j]) : 0.f;
                tw[jj * 64 + lane] = t;
            }
            float hacc0 = bB[lane], hacc1 = bB[lane], hacc2 = bB[lane], hacc3 = bB[lane];
            #pragma unroll
            for (int d4 = 0; d4 < 16; ++d4) {
                float4 t0 = ((const float4*)(tw + 0 * 64))[d4];
                float4 t1 = ((const float4*)(tw + 1 * 64))[d4];
                float4 t2 = ((const float4*)(tw + 2 * 64))[d4];
                float4 t3 = ((const float4*)(tw + 3 * 64))[d4];
                float w0 = wcol[d4 * 4 + 0], w1 = wcol[d4 * 4 + 1];
                float w2 = wcol[d4 * 4 + 2], w3 = wcol[d4 * 4 + 3];
                hacc0 += t0.x * w0 + t0.y * w1 + t0.z * w2 + t0.w * w3;
                hacc1 += t1.x * w0 + t1.y * w1 + t1.z * w2 + t1.w * w3;
                hacc2 += t2.x * w0 + t2.y * w1 + t2.z * w2 + t2.w * w3;
                hacc3 += t3.x * w0 + t3.y * w1 + t3.z * w2 + t3.w * w3;
            }
            float hv[4] = {hacc0, hacc1, hacc2, hacc3};
            #pragma unroll
            for (int jj = 0; jj < 4; ++jj) {
                int m = mb + half * 4 + jj;
                float h = gelu_f(hv[jj]);
                float s1 = h;
                #pragma unroll
                for (int off = 32; off; off >>= 1) s1 += __shfl_xor(s1, off);
                float mu = s1 * (1.f / 64.f);
                float dc = h - mu;
                float s2 = dc * dc;
                #pragma unroll
                for (int off = 32; off; off >>= 1) s2 += __shfl_xor(s2, off);
                float var = s2 * (1.f / 64.f);
                float y = dc * (1.f / sqrtf(var + 1e-5f)) * bG[lane] + bE[lane];
                if (m < NN) Xblk[(size_t)m * DD + lane] = y;
            }
        }
    }
}

// ---------------------------------------------------------------- Wih transpose
// A[192][32000] -> B[32000][192]
__global__ __launch_bounds__(256)
void transpose_kernel(const float* __restrict__ A, float* __restrict__ B)
{
    __shared__ float t[32][33];
    const int i0 = blockIdx.x * 32;
    const int g0 = blockIdx.y * 32;
    const int tx = threadIdx.x, ty = threadIdx.y;
    #pragma unroll
    for (int k = 0; k < 4; ++k)
        t[ty + k * 8][tx] = A[(size_t)(g0 + ty + k * 8) * I_DIM + i0 + tx];
    __syncthreads();
    #pragma unroll
    for (int k = 0; k < 4; ++k)
        B[(size_t)(i0 + ty + k * 8) * 192 + g0 + tx] = t[tx][ty + k * 8];
}

// ---------------------------------------------------------------- GRU pre-GEMM
__global__ __launch_bounds__(192)
void gru_pre_kernel(const float* __restrict__ X, const float* __restrict__ WihT,
                    float* __restrict__ partial, int Trows, int toff, int M)
{
    __shared__ float xs[8][KCH];
    const int tid = threadIdx.x;
    const int rt = blockIdx.x, kc = blockIdx.y;
    const int kbase = kc * KCH;
    const int R0 = rt * 8;
    for (int r = 0; r < 8; ++r) {
        int R = R0 + r;
        int b = R / Trows, tt = R % Trows;
        const float* xr = X + (size_t)(b * 256 + toff + tt) * I_DIM + kbase;
        for (int idx = tid; idx < KCH / 4; idx += 192)
            ((float4*)&xs[r][0])[idx] = ((const float4*)xr)[idx];
    }
    __syncthreads();
    const int g = tid;
    float acc[8];
    #pragma unroll
    for (int r = 0; r < 8; ++r) acc[r] = 0.f;
    for (int i4 = 0; i4 < KCH / 4; ++i4) {
        float4 xv[8];
        #pragma unroll
        for (int r = 0; r < 8; ++r) xv[r] = ((const float4*)&xs[r][0])[i4];
        float w0 = WihT[(size_t)(kbase + i4 * 4 + 0) * 192 + g];
        float w1 = WihT[(size_t)(kbase + i4 * 4 + 1) * 192 + g];
        float w2 = WihT[(size_t)(kbase + i4 * 4 + 2) * 192 + g];
        float w3 = WihT[(size_t)(kbase + i4 * 4 + 3) * 192 + g];
        #pragma unroll
        for (int r = 0; r < 8; ++r)
            acc[r] += xv[r].x * w0 + xv[r].y * w1 + xv[r].z * w2 + xv[r].w * w3;
    }
    #pragma unroll
    for (int r = 0; r < 8; ++r)
        partial[(size_t)kc * M * 192 + (size_t)(R0 + r) * 192 + g] = acc[r];
}

__global__ __launch_bounds__(192)
void gru_reduce_kernel(const float* __restrict__ partial, const float* __restrict__ bih,
                       float* __restrict__ xp, int M)
{
    const int r = blockIdx.x, g = threadIdx.x;
    float acc = bih[g];
    for (int kc = 0; kc < KC; ++kc)
        acc += partial[(size_t)kc * M * 192 + (size_t)r * 192 + g];
    xp[(size_t)r * 192 + g] = acc;
}

// ---------------------------------------------------------------- GRU scan
__global__ __launch_bounds__(768)
void gru_scan_kernel(const float* __restrict__ xp_s, const float* __restrict__ xp_m,
                     const float* __restrict__ xp_l,
                     const float* __restrict__ Whh_s, const float* __restrict__ Whh_m,
                     const float* __restrict__ Whh_l,
                     const float* __restrict__ bhh_s, const float* __restrict__ bhh_m,
                     const float* __restrict__ bhh_l,
                     float* __restrict__ hcat)
{
    __shared__ float h[4][64];
    __shared__ float gh[4][192];
    const int g3 = blockIdx.x;
    const float* xp  = (g3 == 0) ? xp_s : (g3 == 1) ? xp_m : xp_l;
    const float* Whh = (g3 == 0) ? Whh_s : (g3 == 1) ? Whh_m : Whh_l;
    const float* bhh = (g3 == 0) ? bhh_s : (g3 == 1) ? bhh_m : bhh_l;
    const int T = (g3 == 0) ? 10 : (g3 == 1) ? 20 : 256;
    const int tid = threadIdx.x;
    const int b = tid / 192, g = tid % 192;

    float wreg[64];
    #pragma unroll
    for (int k4 = 0; k4 < 16; ++k4) {
        float4 v = *(const float4*)&Whh[g * 64 + k4 * 4];
        wreg[k4 * 4 + 0] = v.x; wreg[k4 * 4 + 1] = v.y;
        wreg[k4 * 4 + 2] = v.z; wreg[k4 * 4 + 3] = v.w;
    }
    const float bh = bhh[g];
    if (tid < 256) h[tid >> 6][tid & 63] = 0.f;
    __syncthreads();

    for (int t = 0; t < T; ++t) {
        float acc = bh;
        #pragma unroll
        for (int k4 = 0; k4 < 16; ++k4) {
            float4 hv = ((const float4*)&h[b][0])[k4];
            acc += hv.x * wreg[k4 * 4 + 0] + hv.y * wreg[k4 * 4 + 1]
                 + hv.z * wreg[k4 * 4 + 2] + hv.w * wreg[k4 * 4 + 3];
        }
        gh[b][g] = acc;
        __syncthreads();
        if (g < 64) {
            const int j = g;
            const float* xpr = xp + (size_t)(b * T + t) * 192;
            float xr = xpr[j], xz = xpr[64 + j], xn = xpr[128 + j];
            float hr = gh[b][j], hz = gh[b][64 + j], hn = gh[b][128 + j];
            float r = 1.f / (1.f + expf(-(xr + hr)));
            float z = 1.f / (1.f + expf(-(xz + hz)));
            float nv = tanhf(xn + r * hn);
            h[b][j] = (1.f - z) * nv + z * h[b][j];
        }
        __syncthreads();
    }
    if (g < 64) hcat[b * 192 + g3 * 64 + g] = h[b][g];
}

// ---------------------------------------------------------------- head
__global__ __launch_bounds__(512)
void head_kernel(const float* __restrict__ hcat,
                 const float* __restrict__ W1, const float* __restrict__ b1,
                 const float* __restrict__ W2, const float* __restrict__ b2,
                 float* __restrict__ out)
{
    __shared__ float hc[4][192];
    __shared__ float h1[4][64];
    const int tid = threadIdx.x;
    // FIX (round 1 bug): block is 512 threads; must stride to cover 768 entries.
    for (int i = tid; i < 768; i += 512) hc[i / 192][i % 192] = hcat[i];
    __syncthreads();
    if (tid < 256) {
        int b = tid >> 6, e = tid & 63;
        float acc = b1[e];
        #pragma unroll
        for (int k = 0; k < 192; ++k) acc += hc[b][k] * W1[e * 192 + k];
        h1[b][e] = gelu_f(acc);
    }
    __syncthreads();
    for (int o = tid; o < 2000; o += 512) {
        int b = o / 500, n = o % 500;
        float acc = b2[n];
        #pragma unroll
        for (int k = 0; k < 64; ++k) acc += h1[b][k] * W2[n * 64 + k];
        out[o] = acc;
    }
}

// ================================================================ launch
extern "C" void kernel_launch(void* const* d_in, const int* in_sizes, int n_in,
                              void* d_out, int out_size, void* d_ws, size_t ws_size,
                              hipStream_t stream)
{
    (void)in_sizes; (void)n_in; (void)out_size; (void)ws_size;
    const float* x    = (const float*)d_in[0];
    const float* ipW  = (const float*)d_in[1];
    const float* ipb  = (const float*)d_in[2];
    const float* fe   = (const float*)d_in[3];
    const float* te   = (const float*)d_in[4];
    const float* glW  = (const float*)d_in[5];
    const float* glb  = (const float*)d_in[6];
    const float* glg  = (const float*)d_in[7];
    const float* glbe = (const float*)d_in[8];
    const float* Wih[3] = {(const float*)d_in[9],  (const float*)d_in[13], (const float*)d_in[17]};
    const float* Whh[3] = {(const float*)d_in[10], (const float*)d_in[14], (const float*)d_in[18]};
    const float* bih[3] = {(const float*)d_in[11], (const float*)d_in[15], (const float*)d_in[19]};
    const float* bhh[3] = {(const float*)d_in[12], (const float*)d_in[16], (const float*)d_in[20]};
    const float* W1 = (const float*)d_in[21];
    const float* b1 = (const float*)d_in[22];
    const float* W2 = (const float*)d_in[23];
    const float* b2 = (const float*)d_in[24];
    float* out = (float*)d_out;

    float* ws      = (float*)d_ws;
    float* X       = ws;                       // 32,768,000
    float* adjT    = X + 32768000;             // 256,000 (500 x 512)
    float* WihT    = adjT + 256000;            // 6,144,000 (reused per GRU)
    float* xp0     = WihT + 6144000;           // 7,680
    float* xp1     = xp0 + 7680;               // 15,360
    float* xp2     = xp1 + 15360;              // 196,608
    float* partial = xp2 + 196608;             // 20*1024*192 = 3,932,160
    float* hcat    = partial + 3932160;        // 768
    float* xp[3] = {xp0, xp1, xp2};

    adj_kernel<<<NN, 512, 0, stream>>>(fe, te, adjT);
    proj_kernel<<<dim3(125, BS_TOT), 256, 0, stream>>>(x, ipW, ipb, X);

    const int smem_bytes = (NN * DD + 8 * 4 * 64 + 3 * 64) * sizeof(float); // 136,960
    hipFuncSetAttribute((const void*)graph_layer_kernel,
                        hipFuncAttributeMaxDynamicSharedMemorySize, smem_bytes);
    for (int i = 0; i < 2; ++i)
        graph_layer_kernel<<<BS_TOT, 512, smem_bytes, stream>>>(
            X, adjT, glW + i * 64 * 64, glb + i * 64, glg + i * 64, glbe + i * 64);

    const int Trows[3] = {10, 20, 256};
    const int toff[3]  = {246, 236, 0};
    for (int gi = 0; gi < 3; ++gi) {
        int M = 4 * Trows[gi];
        transpose_kernel<<<dim3(1000, 6), dim3(32, 8), 0, stream>>>(Wih[gi], WihT);
        gru_pre_kernel<<<dim3(M / 8, KC), 192, 0, stream>>>(X, WihT, partial, Trows[gi], toff[gi], M);
        gru_reduce_kernel<<<M, 192, 0, stream>>>(partial, bih[gi], xp[gi], M);
    }
    gru_scan_kernel<<<3, 768, 0, stream>>>(xp[0], xp[1], xp[2],
                                           Whh[0], Whh[1], Whh[2],
                                           bhh[0], bhh[1], bhh[2], hcat);
    head_kernel<<<1, 512, 0, stream>>>(hcat, W1, b1, W2, b2, out);
}

// Round 4
// 2573.488 us; speedup vs baseline: 2.0703x; 2.0703x over previous
//
#include <hip/hip_runtime.h>
#include <math.h>

#define NN 500
#define DD 64
#define NPAD 512             // adjT padded to [512][512]
#define COLS 65536           // 1024 * 64
#define BS_TOT 1024          // B*S
#define I_DIM 32000          // N*D
#define KS_GRU 20            // K-split for GRU pre-GEMM
#define KSL 1600             // 32000/20

__device__ __forceinline__ float gelu_f(float x) {
    return 0.5f * x * (1.0f + erff(x * 0.70710678118654752440f));
}

// ---------------------------------------------------------------- adjacency
// adjT[m*512 + n] = adj[n][m];  adj[n][:] = softmax_m(from[n]·to[m] / 0.5)
__global__ __launch_bounds__(512)
void adj_kernel(const float* __restrict__ fe, const float* __restrict__ te,
                float* __restrict__ adjT)
{
    __shared__ float fr[32];
    __shared__ float red[8];
    __shared__ float red2[8];
    const int n = blockIdx.x;
    const int tid = threadIdx.x;
    if (tid < 32) fr[tid] = fe[n * 32 + tid];
    __syncthreads();
    const int m = tid;
    float s = -1e30f;
    if (m < NN) {
        float acc = 0.f;
        #pragma unroll
        for (int f = 0; f < 32; ++f) acc += fr[f] * te[m * 32 + f];
        s = acc * 2.0f;   // 1/TEMP
    }
    float v = s;
    #pragma unroll
    for (int off = 32; off; off >>= 1) v = fmaxf(v, __shfl_xor(v, off));
    if ((tid & 63) == 0) red[tid >> 6] = v;
    __syncthreads();
    float bmax = red[0];
    #pragma unroll
    for (int i = 1; i < 8; ++i) bmax = fmaxf(bmax, red[i]);
    float e = (m < NN) ? expf(s - bmax) : 0.f;
    float v2 = e;
    #pragma unroll
    for (int off = 32; off; off >>= 1) v2 += __shfl_xor(v2, off);
    if ((tid & 63) == 0) red2[tid >> 6] = v2;
    __syncthreads();
    float bsum = 0.f;
    #pragma unroll
    for (int i = 0; i < 8; ++i) bsum += red2[i];
    if (m < NN) adjT[(size_t)m * NPAD + n] = e / bsum;
}

// ---------------------------------------------------------------- input proj
// Xp[n][bs][d] = gelu(sum_f x[bs][n][f] * ipW[d][f] + ipb[d])
__global__ __launch_bounds__(256)
void proj_kernel(const float* __restrict__ xin, const float* __restrict__ ipW,
                 const float* __restrict__ ipb, float* __restrict__ Xp)
{
    __shared__ float wT[32][64];   // [f][d]
    __shared__ float xr[16][32];
    const int tid = threadIdx.x;
    const int n = blockIdx.y;
    const int bs0 = blockIdx.x * 16;
    // FIX (round 3 bug): ipW has 64*32 = 2048 elements; previous loop loaded 512.
    for (int idx = tid; idx < 2048; idx += 256) {
        int d = idx >> 5, f = idx & 31;
        wT[f][d] = ipW[idx];
    }
    if (tid < 128) {
        int r = tid >> 3, fq = tid & 7;
        float4 v = *(const float4*)&xin[((size_t)(bs0 + r) * NN + n) * 32 + fq * 4];
        *(float4*)&xr[r][fq * 4] = v;
    }
    __syncthreads();
    const int lane = tid & 63, wv = tid >> 6;
    #pragma unroll
    for (int q = 0; q < 4; ++q) {
        int r = wv * 4 + q;
        float acc = ipb[lane];
        #pragma unroll
        for (int f = 0; f < 32; ++f) acc += xr[r][f] * wT[f][lane];
        Xp[((size_t)n * BS_TOT + bs0 + r) * 64 + lane] = gelu_f(acc);
    }
}

// ---------------------------------------------------------------- agg GEMM
// Cout[m][c] = sum_n adjT[m][n] * Xin[n][c]  + Xin[m][c]  (residual fused)
// M=500(pad512), N=65536, K=500(pad512). Tile 128x128x16, 256 thr, 8x8 micro.
__global__ __launch_bounds__(256)
void agg_gemm_kernel(const float* __restrict__ Xin, const float* __restrict__ adjT,
                     float* __restrict__ Cout)
{
    __shared__ float As[16][132];   // [k][m], padded stride
    __shared__ float Bs[16][128];   // [k][c]
    const int tid = threadIdx.x;
    const int tx = tid & 15, ty = tid >> 4;
    const int c0 = blockIdx.x * 128;
    const int m0 = blockIdx.y * 128;

    const int sa_m = tid >> 2, sa_kq = tid & 3;       // A-stage map (idx, idx+256)
    const int sb_k = tid >> 5, sb_cq = tid & 31;      // B-stage map

    float acc[8][8];
    #pragma unroll
    for (int i = 0; i < 8; ++i)
        #pragma unroll
        for (int j = 0; j < 8; ++j) acc[i][j] = 0.f;

    for (int kc = 0; kc < 32; ++kc) {
        const int k0 = kc * 16;
        // stage A (adjT is fully zero-padded to 512x512)
        #pragma unroll
        for (int l = 0; l < 2; ++l) {
            int m = sa_m + l * 64;
            float4 v = *(const float4*)&adjT[(size_t)(m0 + m) * NPAD + k0 + sa_kq * 4];
            As[sa_kq * 4 + 0][m] = v.x; As[sa_kq * 4 + 1][m] = v.y;
            As[sa_kq * 4 + 2][m] = v.z; As[sa_kq * 4 + 3][m] = v.w;
        }
        // stage B (rows k>=500 are zero)
        #pragma unroll
        for (int l = 0; l < 2; ++l) {
            int k = sb_k + l * 8;
            int kk = k0 + k;
            float4 v = make_float4(0.f, 0.f, 0.f, 0.f);
            if (kk < NN) v = *(const float4*)&Xin[(size_t)kk * COLS + c0 + sb_cq * 4];
            *(float4*)&Bs[k][sb_cq * 4] = v;
        }
        __syncthreads();
        #pragma unroll
        for (int k = 0; k < 16; ++k) {
            float a[8], b[8];
            *(float4*)&a[0] = *(const float4*)&As[k][ty * 4];
            *(float4*)&a[4] = *(const float4*)&As[k][ty * 4 + 64];
            *(float4*)&b[0] = *(const float4*)&Bs[k][tx * 4];
            *(float4*)&b[4] = *(const float4*)&Bs[k][tx * 4 + 64];
            #pragma unroll
            for (int i = 0; i < 8; ++i)
                #pragma unroll
                for (int j = 0; j < 8; ++j) acc[i][j] += a[i] * b[j];
        }
        __syncthreads();
    }
    // epilogue: residual add + store
    #pragma unroll
    for (int i = 0; i < 8; ++i) {
        int m = m0 + ty * 4 + (i & 3) + ((i >= 4) ? 64 : 0);
        if (m < NN) {
            #pragma unroll
            for (int jh = 0; jh < 2; ++jh) {
                int c = c0 + tx * 4 + jh * 64;
                float4 xv = *(const float4*)&Xin[(size_t)m * COLS + c];
                float4 o;
                o.x = acc[i][jh * 4 + 0] + xv.x; o.y = acc[i][jh * 4 + 1] + xv.y;
                o.z = acc[i][jh * 4 + 2] + xv.z; o.w = acc[i][jh * 4 + 3] + xv.w;
                *(float4*)&Cout[(size_t)m * COLS + c] = o;
            }
        }
    }
}

// ---------------------------------------------------------------- h + LN (in-place)
// Xio[n][bs][e] = LN_e( gelu( sum_d Xio[n][bs][d] * glW[e][d] + glb[e] ) )
__global__ __launch_bounds__(256)
void hln_kernel(float* __restrict__ Xio, const float* __restrict__ glW,
                const float* __restrict__ glb, const float* __restrict__ glg,
                const float* __restrict__ glbe)
{
    __shared__ float Wt[64][65];   // [d][e]
    __shared__ float ts[16][64];
    __shared__ float bB[64], bG[64], bE[64];
    const int tid = threadIdx.x;
    const int n = blockIdx.y;
    const int bs0 = blockIdx.x * 16;
    #pragma unroll
    for (int l = 0; l < 4; ++l) {
        int idx = tid + l * 256;       // = e*16 + dq
        int e = idx >> 4, dq = idx & 15;
        float4 v = *(const float4*)&glW[e * 64 + dq * 4];
        Wt[dq * 4 + 0][e] = v.x; Wt[dq * 4 + 1][e] = v.y;
        Wt[dq * 4 + 2][e] = v.z; Wt[dq * 4 + 3][e] = v.w;
    }
    if (tid < 64) { bB[tid] = glb[tid]; bG[tid] = glg[tid]; bE[tid] = glbe[tid]; }
    {
        int r = tid >> 4, dq = tid & 15;
        float4 v = *(const float4*)&Xio[((size_t)n * BS_TOT + bs0 + r) * 64 + dq * 4];
        *(float4*)&ts[r][dq * 4] = v;
    }
    __syncthreads();
    const int lane = tid & 63, wv = tid >> 6;
    #pragma unroll
    for (int q = 0; q < 4; ++q) {
        int r = wv * 4 + q;
        float acc = bB[lane];
        #pragma unroll
        for (int d = 0; d < 64; ++d) acc += ts[r][d] * Wt[d][lane];
        float h = gelu_f(acc);
        float s1 = h;
        #pragma unroll
        for (int off = 32; off; off >>= 1) s1 += __shfl_xor(s1, off);
        float mu = s1 * (1.f / 64.f);
        float dc = h - mu;
        float s2 = dc * dc;
        #pragma unroll
        for (int off = 32; off; off >>= 1) s2 += __shfl_xor(s2, off);
        float var = s2 * (1.f / 64.f);
        float y = dc * (1.f / sqrtf(var + 1e-5f)) * bG[lane] + bE[lane];
        Xio[((size_t)n * BS_TOT + bs0 + r) * 64 + lane] = y;
    }
}

// ---------------------------------------------------------------- Wih transpose
// A[192][32000] -> B[32000][192]
__global__ __launch_bounds__(256)
void transpose_kernel(const float* __restrict__ A, float* __restrict__ B)
{
    __shared__ float t[32][33];
    const int i0 = blockIdx.x * 32;
    const int g0 = blockIdx.y * 32;
    const int tx = threadIdx.x, ty = threadIdx.y;
    #pragma unroll
    for (int k = 0; k < 4; ++k)
        t[ty + k * 8][tx] = A[(size_t)(g0 + ty + k * 8) * I_DIM + i0 + tx];
    __syncthreads();
    #pragma unroll
    for (int k = 0; k < 4; ++k)
        B[(size_t)(i0 + ty + k * 8) * 192 + g0 + tx] = t[tx][ty + k * 8];
}

// ---------------------------------------------------------------- GRU pre-GEMM
// partial[ks][R][g] = sum_{k in slice} xflat[R][k] * WihT[k][g]
// xflat[R][k=n*64+d] = Xp[n][bt(R)][d].  Tile TM=64, TN=192, TK=16.
__global__ __launch_bounds__(256)
void gru_pre_kernel(const float* __restrict__ Xp, const float* __restrict__ WihT,
                    float* __restrict__ partial, int Trows, int toff, int M)
{
    __shared__ float As[16][68];    // [k][r]
    __shared__ float Bs[16][192];   // [k][g]
    const int tid = threadIdx.x;
    const int tx = tid & 15, ty = tid >> 4;
    const int R0 = blockIdx.x * 64;
    const int ks = blockIdx.y;

    // A-stage row map
    const int rs = tid >> 2, dqs = tid & 3;
    const int Rr = R0 + rs;
    const bool vld = (Rr < M);
    int bt = 0;
    if (vld) { int b = Rr / Trows, t = Rr - b * Trows; bt = b * 256 + toff + t; }
    // B-stage maps (3 x 256 = 768 = 16k x 48q)
    int bk[3], bg[3];
    #pragma unroll
    for (int l = 0; l < 3; ++l) { int idx = tid + l * 256; bk[l] = idx / 48; bg[l] = idx % 48; }

    float acc[4][12];
    #pragma unroll
    for (int i = 0; i < 4; ++i)
        #pragma unroll
        for (int j = 0; j < 12; ++j) acc[i][j] = 0.f;

    for (int c = 0; c < KSL / 16; ++c) {
        const int k0 = ks * KSL + c * 16;
        const int nn = k0 >> 6, d0 = k0 & 63;
        float4 v = make_float4(0.f, 0.f, 0.f, 0.f);
        if (vld) v = *(const float4*)&Xp[((size_t)nn * BS_TOT + bt) * 64 + d0 + dqs * 4];
        As[dqs * 4 + 0][rs] = v.x; As[dqs * 4 + 1][rs] = v.y;
        As[dqs * 4 + 2][rs] = v.z; As[dqs * 4 + 3][rs] = v.w;
        #pragma unroll
        for (int l = 0; l < 3; ++l) {
            float4 w = *(const float4*)&WihT[(size_t)(k0 + bk[l]) * 192 + bg[l] * 4];
            *(float4*)&Bs[bk[l]][bg[l] * 4] = w;
        }
        __syncthreads();
        #pragma unroll
        for (int k = 0; k < 16; ++k) {
            float a[4], b[12];
            *(float4*)&a[0] = *(const float4*)&As[k][ty * 4];
            *(float4*)&b[0] = *(const float4*)&Bs[k][tx * 12];
            *(float4*)&b[4] = *(const float4*)&Bs[k][tx * 12 + 4];
            *(float4*)&b[8] = *(const float4*)&Bs[k][tx * 12 + 8];
            #pragma unroll
            for (int i = 0; i < 4; ++i)
                #pragma unroll
                for (int j = 0; j < 12; ++j) acc[i][j] += a[i] * b[j];
        }
        __syncthreads();
    }
    #pragma unroll
    for (int i = 0; i < 4; ++i) {
        int R = R0 + ty * 4 + i;
        if (R < M) {
            #pragma unroll
            for (int j4 = 0; j4 < 3; ++j4)
                *(float4*)&partial[((size_t)ks * M + R) * 192 + tx * 12 + j4 * 4] =
                    *(float4*)&acc[i][j4 * 4];
        }
    }
}

__global__ __launch_bounds__(192)
void gru_reduce_kernel(const float* __restrict__ partial, const float* __restrict__ bih,
                       float* __restrict__ xp, int M)
{
    const int r = blockIdx.x, g = threadIdx.x;
    float acc = bih[g];
    for (int ks = 0; ks < KS_GRU; ++ks)
        acc += partial[((size_t)ks * M + r) * 192 + g];
    xp[(size_t)r * 192 + g] = acc;
}

// ---------------------------------------------------------------- GRU scan
__global__ __launch_bounds__(768)
void gru_scan_kernel(const float* __restrict__ xp_s, const float* __restrict__ xp_m,
                     const float* __restrict__ xp_l,
                     const float* __restrict__ Whh_s, const float* __restrict__ Whh_m,
                     const float* __restrict__ Whh_l,
                     const float* __restrict__ bhh_s, const float* __restrict__ bhh_m,
                     const float* __restrict__ bhh_l,
                     float* __restrict__ hcat)
{
    __shared__ float h[4][64];
    __shared__ float gh[4][192];
    const int g3 = blockIdx.x;
    const float* xp  = (g3 == 0) ? xp_s : (g3 == 1) ? xp_m : xp_l;
    const float* Whh = (g3 == 0) ? Whh_s : (g3 == 1) ? Whh_m : Whh_l;
    const float* bhh = (g3 == 0) ? bhh_s : (g3 == 1) ? bhh_m : bhh_l;
    const int T = (g3 == 0) ? 10 : (g3 == 1) ? 20 : 256;
    const int tid = threadIdx.x;
    const int b = tid / 192, g = tid % 192;

    float wreg[64];
    #pragma unroll
    for (int k4 = 0; k4 < 16; ++k4) {
        float4 v = *(const float4*)&Whh[g * 64 + k4 * 4];
        wreg[k4 * 4 + 0] = v.x; wreg[k4 * 4 + 1] = v.y;
        wreg[k4 * 4 + 2] = v.z; wreg[k4 * 4 + 3] = v.w;
    }
    const float bh = bhh[g];
    if (tid < 256) h[tid >> 6][tid & 63] = 0.f;
    __syncthreads();

    for (int t = 0; t < T; ++t) {
        float acc = bh;
        #pragma unroll
        for (int k4 = 0; k4 < 16; ++k4) {
            float4 hv = ((const float4*)&h[b][0])[k4];
            acc += hv.x * wreg[k4 * 4 + 0] + hv.y * wreg[k4 * 4 + 1]
                 + hv.z * wreg[k4 * 4 + 2] + hv.w * wreg[k4 * 4 + 3];
        }
        gh[b][g] = acc;
        __syncthreads();
        if (g < 64) {
            const int j = g;
            const float* xpr = xp + (size_t)(b * T + t) * 192;
            float xr = xpr[j], xz = xpr[64 + j], xn = xpr[128 + j];
            float hr = gh[b][j], hz = gh[b][64 + j], hn = gh[b][128 + j];
            float r = 1.f / (1.f + expf(-(xr + hr)));
            float z = 1.f / (1.f + expf(-(xz + hz)));
            float nv = tanhf(xn + r * hn);
            h[b][j] = (1.f - z) * nv + z * h[b][j];
        }
        __syncthreads();
    }
    if (g < 64) hcat[b * 192 + g3 * 64 + g] = h[b][g];
}

// ---------------------------------------------------------------- head
__global__ __launch_bounds__(512)
void head_kernel(const float* __restrict__ hcat,
                 const float* __restrict__ W1, const float* __restrict__ b1,
                 const float* __restrict__ W2, const float* __restrict__ b2,
                 float* __restrict__ out)
{
    __shared__ float hc[4][192];
    __shared__ float h1[4][64];
    const int tid = threadIdx.x;
    for (int i = tid; i < 768; i += 512) hc[i / 192][i % 192] = hcat[i];
    __syncthreads();
    if (tid < 256) {
        int b = tid >> 6, e = tid & 63;
        float acc = b1[e];
        #pragma unroll
        for (int k = 0; k < 192; ++k) acc += hc[b][k] * W1[e * 192 + k];
        h1[b][e] = gelu_f(acc);
    }
    __syncthreads();
    for (int o = tid; o < 2000; o += 512) {
        int b = o / 500, n = o % 500;
        float acc = b2[n];
        #pragma unroll
        for (int k = 0; k < 64; ++k) acc += h1[b][k] * W2[n * 64 + k];
        out[o] = acc;
    }
}

// ================================================================ launch
extern "C" void kernel_launch(void* const* d_in, const int* in_sizes, int n_in,
                              void* d_out, int out_size, void* d_ws, size_t ws_size,
                              hipStream_t stream)
{
    (void)in_sizes; (void)n_in; (void)out_size; (void)ws_size;
    const float* x    = (const float*)d_in[0];
    const float* ipW  = (const float*)d_in[1];
    const float* ipb  = (const float*)d_in[2];
    const float* fe   = (const float*)d_in[3];
    const float* te   = (const float*)d_in[4];
    const float* glW  = (const float*)d_in[5];
    const float* glb  = (const float*)d_in[6];
    const float* glg  = (const float*)d_in[7];
    const float* glbe = (const float*)d_in[8];
    const float* Wih[3] = {(const float*)d_in[9],  (const float*)d_in[13], (const float*)d_in[17]};
    const float* Whh[3] = {(const float*)d_in[10], (const float*)d_in[14], (const float*)d_in[18]};
    const float* bih[3] = {(const float*)d_in[11], (const float*)d_in[15], (const float*)d_in[19]};
    const float* bhh[3] = {(const float*)d_in[12], (const float*)d_in[16], (const float*)d_in[20]};
    const float* W1 = (const float*)d_in[21];
    const float* b1 = (const float*)d_in[22];
    const float* W2 = (const float*)d_in[23];
    const float* b2 = (const float*)d_in[24];
    float* out = (float*)d_out;

    float* ws   = (float*)d_ws;
    float* A    = ws;                  // 32,768,000  (500*65536)  X ping
    float* Bb   = A + 32768000;        // 32,768,000              X pong
    float* adjT = Bb + 32768000;       // 262,144 (512*512)
    // GRU-phase scratch overlaps Bb (dead after layer-2 GEMM):
    float* WihT    = Bb;               // 6,144,000
    float* partial = Bb + 6144000;     // 20*1024*192 = 3,932,160
    float* xp0     = Bb + 10076160;    // 7,680
    float* xp1     = xp0 + 7680;       // 15,360
    float* xp2     = xp1 + 15360;      // 196,608
    float* hcat    = xp2 + 196608;     // 768
    float* xp[3] = {xp0, xp1, xp2};

    hipMemsetAsync(adjT, 0, (size_t)NPAD * NPAD * sizeof(float), stream);
    adj_kernel<<<NN, 512, 0, stream>>>(fe, te, adjT);
    proj_kernel<<<dim3(64, NN), 256, 0, stream>>>(x, ipW, ipb, A);

    // layer 1: A -> Bb (agg+residual), then h+LN in-place on Bb
    agg_gemm_kernel<<<dim3(512, 4), 256, 0, stream>>>(A, adjT, Bb);
    hln_kernel<<<dim3(64, NN), 256, 0, stream>>>(Bb, glW, glb, glg, glbe);
    // layer 2: Bb -> A, then in-place on A
    agg_gemm_kernel<<<dim3(512, 4), 256, 0, stream>>>(Bb, adjT, A);
    hln_kernel<<<dim3(64, NN), 256, 0, stream>>>(A, glW + 4096, glb + 64, glg + 64, glbe + 64);

    const int Trows[3] = {10, 20, 256};
    const int toff[3]  = {246, 236, 0};
    const int Mg[3]    = {40, 80, 1024};
    for (int gi = 0; gi < 3; ++gi) {
        transpose_kernel<<<dim3(1000, 6), dim3(32, 8), 0, stream>>>(Wih[gi], WihT);
        int mt = (Mg[gi] + 63) / 64;
        gru_pre_kernel<<<dim3(mt, KS_GRU), 256, 0, stream>>>(A, WihT, partial,
                                                             Trows[gi], toff[gi], Mg[gi]);
        gru_reduce_kernel<<<Mg[gi], 192, 0, stream>>>(partial, bih[gi], xp[gi], Mg[gi]);
    }
    gru_scan_kernel<<<3, 768, 0, stream>>>(xp[0], xp[1], xp[2],
                                           Whh[0], Whh[1], Whh[2],
                                           bhh[0], bhh[1], bhh[2], hcat);
    head_kernel<<<1, 512, 0, stream>>>(hcat, W1, b1, W2, b2, out);
}

// Round 5
// 2265.534 us; speedup vs baseline: 2.3518x; 1.1359x over previous
//
#include <hip/hip_runtime.h>
#include <math.h>

#define NN 500
#define DD 64
#define NPAD 512             // adjT padded to [512][512]
#define COLS 65536           // 1024 * 64
#define BS_TOT 1024          // B*S
#define I_DIM 32000          // N*D
#define KS_GRU 20            // K-split for GRU pre-GEMM
#define KSL 1600             // 32000/20

typedef __attribute__((ext_vector_type(8))) short bf16x8;
typedef __attribute__((ext_vector_type(4))) float f32x4;

__device__ __forceinline__ float gelu_f(float x) {
    return 0.5f * x * (1.0f + erff(x * 0.70710678118654752440f));
}

__device__ __forceinline__ unsigned short bf16_rn(float x) {
    unsigned int u = __float_as_uint(x);
    unsigned int r = u + 0x7FFFu + ((u >> 16) & 1u);
    return (unsigned short)(r >> 16);
}
__device__ __forceinline__ float bf16_tof(unsigned short h) {
    return __uint_as_float(((unsigned int)h) << 16);
}

// ---------------------------------------------------------------- adjacency
__global__ __launch_bounds__(512)
void adj_kernel(const float* __restrict__ fe, const float* __restrict__ te,
                float* __restrict__ adjT)
{
    __shared__ float fr[32];
    __shared__ float red[8];
    __shared__ float red2[8];
    const int n = blockIdx.x;
    const int tid = threadIdx.x;
    if (tid < 32) fr[tid] = fe[n * 32 + tid];
    __syncthreads();
    const int m = tid;
    float s = -1e30f;
    if (m < NN) {
        float acc = 0.f;
        #pragma unroll
        for (int f = 0; f < 32; ++f) acc += fr[f] * te[m * 32 + f];
        s = acc * 2.0f;   // 1/TEMP
    }
    float v = s;
    #pragma unroll
    for (int off = 32; off; off >>= 1) v = fmaxf(v, __shfl_xor(v, off));
    if ((tid & 63) == 0) red[tid >> 6] = v;
    __syncthreads();
    float bmax = red[0];
    #pragma unroll
    for (int i = 1; i < 8; ++i) bmax = fmaxf(bmax, red[i]);
    float e = (m < NN) ? expf(s - bmax) : 0.f;
    float v2 = e;
    #pragma unroll
    for (int off = 32; off; off >>= 1) v2 += __shfl_xor(v2, off);
    if ((tid & 63) == 0) red2[tid >> 6] = v2;
    __syncthreads();
    float bsum = 0.f;
    #pragma unroll
    for (int i = 0; i < 8; ++i) bsum += red2[i];
    if (m < NN) adjT[(size_t)m * NPAD + n] = e / bsum;
}

// ---------------------------------------------------------------- input proj
// Xp[n][bs][d] = gelu(sum_f x[bs][n][f] * ipW[d][f] + ipb[d])
__global__ __launch_bounds__(256)
void proj_kernel(const float* __restrict__ xin, const float* __restrict__ ipW,
                 const float* __restrict__ ipb, float* __restrict__ Xp)
{
    __shared__ float wT[32][64];   // [f][d]
    __shared__ float xr[16][32];
    const int tid = threadIdx.x;
    const int n = blockIdx.y;
    const int bs0 = blockIdx.x * 16;
    for (int idx = tid; idx < 2048; idx += 256) {
        int d = idx >> 5, f = idx & 31;
        wT[f][d] = ipW[idx];
    }
    if (tid < 128) {
        int r = tid >> 3, fq = tid & 7;
        float4 v = *(const float4*)&xin[((size_t)(bs0 + r) * NN + n) * 32 + fq * 4];
        *(float4*)&xr[r][fq * 4] = v;
    }
    __syncthreads();
    const int lane = tid & 63, wv = tid >> 6;
    #pragma unroll
    for (int q = 0; q < 4; ++q) {
        int r = wv * 4 + q;
        float acc = ipb[lane];
        #pragma unroll
        for (int f = 0; f < 32; ++f) acc += xr[r][f] * wT[f][lane];
        Xp[((size_t)n * BS_TOT + bs0 + r) * 64 + lane] = gelu_f(acc);
    }
}

// ---------------------------------------------------------------- agg GEMM (split-bf16 MFMA)
// Cout[m][c] = sum_n adjT[m][n] * Xin[n][c] + Xin[m][c]
// M=512, N=65536, K=512. Block tile 128x128, 4 waves (2x2 of 64x64), BK=32.
// x = hi + lo (bf16 each); x*y ~= hi*hi + hi*lo + lo*hi (3 MFMAs, err ~2^-18).
// LDS tiles [row][k] bf16, row stride 40 shorts (80B), XOR swizzle on k-bytes.
__device__ __forceinline__ int swz_k(int row, int kbyte) {
    return kbyte ^ (((row >> 3) & 3) << 4);
}

__global__ __launch_bounds__(256)
void agg_mfma_kernel(const float* __restrict__ Xin, const float* __restrict__ adjT,
                     float* __restrict__ Cout)
{
    __shared__ short Ah[128 * 40];
    __shared__ short Al[128 * 40];
    __shared__ short Bh[128 * 40];
    __shared__ short Bl[128 * 40];

    const int tid  = threadIdx.x;
    const int lane = tid & 63;
    const int wave = tid >> 6;
    const int wm = (wave >> 1) * 64;
    const int wc = (wave & 1) * 64;
    const int q = lane >> 4, r16 = lane & 15;
    const int c0 = blockIdx.x * 128;
    const int m0 = blockIdx.y * 128;

    // staging maps
    const int sa_m = tid >> 1, sa_kh = tid & 1;     // A: row m, k-half (16 k each)
    const int sb_c = tid & 127, sb_kh = tid >> 7;   // B: col c, k-half

    f32x4 acc[4][4];
    #pragma unroll
    for (int i = 0; i < 4; ++i)
        #pragma unroll
        for (int j = 0; j < 4; ++j) acc[i][j] = (f32x4){0.f, 0.f, 0.f, 0.f};

    for (int kc = 0; kc < 16; ++kc) {
        const int k0 = kc * 32;
        // ---- stage A (adjT zero-padded to 512x512, unguarded)
        {
            const float* src = &adjT[(size_t)(m0 + sa_m) * NPAD + k0 + sa_kh * 16];
            char* rowH = (char*)Ah + sa_m * 80;
            char* rowL = (char*)Al + sa_m * 80;
            #pragma unroll
            for (int qd = 0; qd < 4; ++qd) {
                float4 v = ((const float4*)src)[qd];
                short4 h4, l4;
                h4.x = (short)bf16_rn(v.x); l4.x = (short)bf16_rn(v.x - bf16_tof(h4.x));
                h4.y = (short)bf16_rn(v.y); l4.y = (short)bf16_rn(v.y - bf16_tof(h4.y));
                h4.z = (short)bf16_rn(v.z); l4.z = (short)bf16_rn(v.z - bf16_tof(h4.z));
                h4.w = (short)bf16_rn(v.w); l4.w = (short)bf16_rn(v.w - bf16_tof(h4.w));
                int kb = swz_k(sa_m, sa_kh * 32 + qd * 8);
                *(short4*)(rowH + kb) = h4;
                *(short4*)(rowL + kb) = l4;
            }
        }
        // ---- stage B transposed: Bt[c][k] (guard k >= 500 -> 0)
        {
            const size_t cb = (size_t)(c0 + sb_c);
            char* rowH = (char*)Bh + sb_c * 80;
            char* rowL = (char*)Bl + sb_c * 80;
            #pragma unroll
            for (int qd = 0; qd < 4; ++qd) {
                float xv[4];
                #pragma unroll
                for (int e = 0; e < 4; ++e) {
                    int kk = k0 + sb_kh * 16 + qd * 4 + e;
                    xv[e] = (kk < NN) ? Xin[(size_t)kk * COLS + cb] : 0.f;
                }
                short4 h4, l4;
                h4.x = (short)bf16_rn(xv[0]); l4.x = (short)bf16_rn(xv[0] - bf16_tof(h4.x));
                h4.y = (short)bf16_rn(xv[1]); l4.y = (short)bf16_rn(xv[1] - bf16_tof(h4.y));
                h4.z = (short)bf16_rn(xv[2]); l4.z = (short)bf16_rn(xv[2] - bf16_tof(h4.z));
                h4.w = (short)bf16_rn(xv[3]); l4.w = (short)bf16_rn(xv[3] - bf16_tof(h4.w));
                int kb = swz_k(sb_c, sb_kh * 32 + qd * 8);
                *(short4*)(rowH + kb) = h4;
                *(short4*)(rowL + kb) = l4;
            }
        }
        __syncthreads();
        // ---- fragments + MFMA
        bf16x8 ah[4], al[4];
        #pragma unroll
        for (int mi = 0; mi < 4; ++mi) {
            int row = wm + mi * 16 + r16;
            int kb = swz_k(row, q * 16);
            ah[mi] = *(const bf16x8*)((const char*)Ah + row * 80 + kb);
            al[mi] = *(const bf16x8*)((const char*)Al + row * 80 + kb);
        }
        #pragma unroll
        for (int ci = 0; ci < 4; ++ci) {
            int row = wc + ci * 16 + r16;
            int kb = swz_k(row, q * 16);
            bf16x8 bh = *(const bf16x8*)((const char*)Bh + row * 80 + kb);
            bf16x8 bl = *(const bf16x8*)((const char*)Bl + row * 80 + kb);
            #pragma unroll
            for (int mi = 0; mi < 4; ++mi) {
                acc[mi][ci] = __builtin_amdgcn_mfma_f32_16x16x32_bf16(ah[mi], bh, acc[mi][ci], 0, 0, 0);
                acc[mi][ci] = __builtin_amdgcn_mfma_f32_16x16x32_bf16(ah[mi], bl, acc[mi][ci], 0, 0, 0);
                acc[mi][ci] = __builtin_amdgcn_mfma_f32_16x16x32_bf16(al[mi], bh, acc[mi][ci], 0, 0, 0);
            }
        }
        __syncthreads();
    }
    // ---- epilogue: residual + store. D frag: row=(lane>>4)*4+r, col=lane&15.
    #pragma unroll
    for (int mi = 0; mi < 4; ++mi) {
        #pragma unroll
        for (int r = 0; r < 4; ++r) {
            int m = m0 + wm + mi * 16 + q * 4 + r;
            if (m < NN) {
                #pragma unroll
                for (int ci = 0; ci < 4; ++ci) {
                    size_t idx = (size_t)m * COLS + c0 + wc + ci * 16 + r16;
                    Cout[idx] = acc[mi][ci][r] + Xin[idx];
                }
            }
        }
    }
}

// ---------------------------------------------------------------- h + LN (in-place)
__global__ __launch_bounds__(256)
void hln_kernel(float* __restrict__ Xio, const float* __restrict__ glW,
                const float* __restrict__ glb, const float* __restrict__ glg,
                const float* __restrict__ glbe)
{
    __shared__ float Wt[64][65];   // [d][e]
    __shared__ float ts[16][64];
    __shared__ float bB[64], bG[64], bE[64];
    const int tid = threadIdx.x;
    const int n = blockIdx.y;
    const int bs0 = blockIdx.x * 16;
    #pragma unroll
    for (int l = 0; l < 4; ++l) {
        int idx = tid + l * 256;       // = e*16 + dq
        int e = idx >> 4, dq = idx & 15;
        float4 v = *(const float4*)&glW[e * 64 + dq * 4];
        Wt[dq * 4 + 0][e] = v.x; Wt[dq * 4 + 1][e] = v.y;
        Wt[dq * 4 + 2][e] = v.z; Wt[dq * 4 + 3][e] = v.w;
    }
    if (tid < 64) { bB[tid] = glb[tid]; bG[tid] = glg[tid]; bE[tid] = glbe[tid]; }
    {
        int r = tid >> 4, dq = tid & 15;
        float4 v = *(const float4*)&Xio[((size_t)n * BS_TOT + bs0 + r) * 64 + dq * 4];
        *(float4*)&ts[r][dq * 4] = v;
    }
    __syncthreads();
    const int lane = tid & 63, wv = tid >> 6;
    #pragma unroll
    for (int q = 0; q < 4; ++q) {
        int r = wv * 4 + q;
        float acc = bB[lane];
        #pragma unroll
        for (int d = 0; d < 64; ++d) acc += ts[r][d] * Wt[d][lane];
        float h = gelu_f(acc);
        float s1 = h;
        #pragma unroll
        for (int off = 32; off; off >>= 1) s1 += __shfl_xor(s1, off);
        float mu = s1 * (1.f / 64.f);
        float dc = h - mu;
        float s2 = dc * dc;
        #pragma unroll
        for (int off = 32; off; off >>= 1) s2 += __shfl_xor(s2, off);
        float var = s2 * (1.f / 64.f);
        float y = dc * (1.f / sqrtf(var + 1e-5f)) * bG[lane] + bE[lane];
        Xio[((size_t)n * BS_TOT + bs0 + r) * 64 + lane] = y;
    }
}

// ---------------------------------------------------------------- Wih transpose
__global__ __launch_bounds__(256)
void transpose_kernel(const float* __restrict__ A, float* __restrict__ B)
{
    __shared__ float t[32][33];
    const int i0 = blockIdx.x * 32;
    const int g0 = blockIdx.y * 32;
    const int tx = threadIdx.x, ty = threadIdx.y;
    #pragma unroll
    for (int k = 0; k < 4; ++k)
        t[ty + k * 8][tx] = A[(size_t)(g0 + ty + k * 8) * I_DIM + i0 + tx];
    __syncthreads();
    #pragma unroll
    for (int k = 0; k < 4; ++k)
        B[(size_t)(i0 + ty + k * 8) * 192 + g0 + tx] = t[tx][ty + k * 8];
}

// ---------------------------------------------------------------- GRU pre-GEMM
__global__ __launch_bounds__(256)
void gru_pre_kernel(const float* __restrict__ Xp, const float* __restrict__ WihT,
                    float* __restrict__ partial, int Trows, int toff, int M)
{
    __shared__ float As[16][68];    // [k][r]
    __shared__ float Bs[16][192];   // [k][g]
    const int tid = threadIdx.x;
    const int tx = tid & 15, ty = tid >> 4;
    const int R0 = blockIdx.x * 64;
    const int ks = blockIdx.y;

    const int rs = tid >> 2, dqs = tid & 3;
    const int Rr = R0 + rs;
    const bool vld = (Rr < M);
    int bt = 0;
    if (vld) { int b = Rr / Trows, t = Rr - b * Trows; bt = b * 256 + toff + t; }
    int bk[3], bg[3];
    #pragma unroll
    for (int l = 0; l < 3; ++l) { int idx = tid + l * 256; bk[l] = idx / 48; bg[l] = idx % 48; }

    float acc[4][12];
    #pragma unroll
    for (int i = 0; i < 4; ++i)
        #pragma unroll
        for (int j = 0; j < 12; ++j) acc[i][j] = 0.f;

    for (int c = 0; c < KSL / 16; ++c) {
        const int k0 = ks * KSL + c * 16;
        const int nn = k0 >> 6, d0 = k0 & 63;
        float4 v = make_float4(0.f, 0.f, 0.f, 0.f);
        if (vld) v = *(const float4*)&Xp[((size_t)nn * BS_TOT + bt) * 64 + d0 + dqs * 4];
        As[dqs * 4 + 0][rs] = v.x; As[dqs * 4 + 1][rs] = v.y;
        As[dqs * 4 + 2][rs] = v.z; As[dqs * 4 + 3][rs] = v.w;
        #pragma unroll
        for (int l = 0; l < 3; ++l) {
            float4 w = *(const float4*)&WihT[(size_t)(k0 + bk[l]) * 192 + bg[l] * 4];
            *(float4*)&Bs[bk[l]][bg[l] * 4] = w;
        }
        __syncthreads();
        #pragma unroll
        for (int k = 0; k < 16; ++k) {
            float a[4], b[12];
            *(float4*)&a[0] = *(const float4*)&As[k][ty * 4];
            *(float4*)&b[0] = *(const float4*)&Bs[k][tx * 12];
            *(float4*)&b[4] = *(const float4*)&Bs[k][tx * 12 + 4];
            *(float4*)&b[8] = *(const float4*)&Bs[k][tx * 12 + 8];
            #pragma unroll
            for (int i = 0; i < 4; ++i)
                #pragma unroll
                for (int j = 0; j < 12; ++j) acc[i][j] += a[i] * b[j];
        }
        __syncthreads();
    }
    #pragma unroll
    for (int i = 0; i < 4; ++i) {
        int R = R0 + ty * 4 + i;
        if (R < M) {
            #pragma unroll
            for (int j4 = 0; j4 < 3; ++j4)
                *(float4*)&partial[((size_t)ks * M + R) * 192 + tx * 12 + j4 * 4] =
                    *(float4*)&acc[i][j4 * 4];
        }
    }
}

__global__ __launch_bounds__(192)
void gru_reduce_kernel(const float* __restrict__ partial, const float* __restrict__ bih,
                       float* __restrict__ xp, int M)
{
    const int r = blockIdx.x, g = threadIdx.x;
    float acc = bih[g];
    for (int ks = 0; ks < KS_GRU; ++ks)
        acc += partial[((size_t)ks * M + r) * 192 + g];
    xp[(size_t)r * 192 + g] = acc;
}

// ---------------------------------------------------------------- GRU scan
__global__ __launch_bounds__(768)
void gru_scan_kernel(const float* __restrict__ xp_s, const float* __restrict__ xp_m,
                     const float* __restrict__ xp_l,
                     const float* __restrict__ Whh_s, const float* __restrict__ Whh_m,
                     const float* __restrict__ Whh_l,
                     const float* __restrict__ bhh_s, const float* __restrict__ bhh_m,
                     const float* __restrict__ bhh_l,
                     float* __restrict__ hcat)
{
    __shared__ float h[4][64];
    __shared__ float gh[4][192];
    const int g3 = blockIdx.x;
    const float* xp  = (g3 == 0) ? xp_s : (g3 == 1) ? xp_m : xp_l;
    const float* Whh = (g3 == 0) ? Whh_s : (g3 == 1) ? Whh_m : Whh_l;
    const float* bhh = (g3 == 0) ? bhh_s : (g3 == 1) ? bhh_m : bhh_l;
    const int T = (g3 == 0) ? 10 : (g3 == 1) ? 20 : 256;
    const int tid = threadIdx.x;
    const int b = tid / 192, g = tid % 192;

    float wreg[64];
    #pragma unroll
    for (int k4 = 0; k4 < 16; ++k4) {
        float4 v = *(const float4*)&Whh[g * 64 + k4 * 4];
        wreg[k4 * 4 + 0] = v.x; wreg[k4 * 4 + 1] = v.y;
        wreg[k4 * 4 + 2] = v.z; wreg[k4 * 4 + 3] = v.w;
    }
    const float bh = bhh[g];
    if (tid < 256) h[tid >> 6][tid & 63] = 0.f;
    __syncthreads();

    for (int t = 0; t < T; ++t) {
        float acc = bh;
        #pragma unroll
        for (int k4 = 0; k4 < 16; ++k4) {
            float4 hv = ((const float4*)&h[b][0])[k4];
            acc += hv.x * wreg[k4 * 4 + 0] + hv.y * wreg[k4 * 4 + 1]
                 + hv.z * wreg[k4 * 4 + 2] + hv.w * wreg[k4 * 4 + 3];
        }
        gh[b][g] = acc;
        __syncthreads();
        if (g < 64) {
            const int j = g;
            const float* xpr = xp + (size_t)(b * T + t) * 192;
            float xr = xpr[j], xz = xpr[64 + j], xn = xpr[128 + j];
            float hr = gh[b][j], hz = gh[b][64 + j], hn = gh[b][128 + j];
            float r = 1.f / (1.f + expf(-(xr + hr)));
            float z = 1.f / (1.f + expf(-(xz + hz)));
            float nv = tanhf(xn + r * hn);
            h[b][j] = (1.f - z) * nv + z * h[b][j];
        }
        __syncthreads();
    }
    if (g < 64) hcat[b * 192 + g3 * 64 + g] = h[b][g];
}

// ---------------------------------------------------------------- head
__global__ __launch_bounds__(512)
void head_kernel(const float* __restrict__ hcat,
                 const float* __restrict__ W1, const float* __restrict__ b1,
                 const float* __restrict__ W2, const float* __restrict__ b2,
                 float* __restrict__ out)
{
    __shared__ float hc[4][192];
    __shared__ float h1[4][64];
    const int tid = threadIdx.x;
    for (int i = tid; i < 768; i += 512) hc[i / 192][i % 192] = hcat[i];
    __syncthreads();
    if (tid < 256) {
        int b = tid >> 6, e = tid & 63;
        float acc = b1[e];
        #pragma unroll
        for (int k = 0; k < 192; ++k) acc += hc[b][k] * W1[e * 192 + k];
        h1[b][e] = gelu_f(acc);
    }
    __syncthreads();
    for (int o = tid; o < 2000; o += 512) {
        int b = o / 500, n = o % 500;
        float acc = b2[n];
        #pragma unroll
        for (int k = 0; k < 64; ++k) acc += h1[b][k] * W2[n * 64 + k];
        out[o] = acc;
    }
}

// ================================================================ launch
extern "C" void kernel_launch(void* const* d_in, const int* in_sizes, int n_in,
                              void* d_out, int out_size, void* d_ws, size_t ws_size,
                              hipStream_t stream)
{
    (void)in_sizes; (void)n_in; (void)out_size; (void)ws_size;
    const float* x    = (const float*)d_in[0];
    const float* ipW  = (const float*)d_in[1];
    const float* ipb  = (const float*)d_in[2];
    const float* fe   = (const float*)d_in[3];
    const float* te   = (const float*)d_in[4];
    const float* glW  = (const float*)d_in[5];
    const float* glb  = (const float*)d_in[6];
    const float* glg  = (const float*)d_in[7];
    const float* glbe = (const float*)d_in[8];
    const float* Wih[3] = {(const float*)d_in[9],  (const float*)d_in[13], (const float*)d_in[17]};
    const float* Whh[3] = {(const float*)d_in[10], (const float*)d_in[14], (const float*)d_in[18]};
    const float* bih[3] = {(const float*)d_in[11], (const float*)d_in[15], (const float*)d_in[19]};
    const float* bhh[3] = {(const float*)d_in[12], (const float*)d_in[16], (const float*)d_in[20]};
    const float* W1 = (const float*)d_in[21];
    const float* b1 = (const float*)d_in[22];
    const float* W2 = (const float*)d_in[23];
    const float* b2 = (const float*)d_in[24];
    float* out = (float*)d_out;

    float* ws   = (float*)d_ws;
    float* A    = ws;                  // 32,768,000  (500*65536)  X ping
    float* Bb   = A + 32768000;        // 32,768,000              X pong
    float* adjT = Bb + 32768000;       // 262,144 (512*512)
    // GRU-phase scratch overlaps Bb (dead after layer-2 GEMM):
    float* WihT    = Bb;               // 6,144,000
    float* partial = Bb + 6144000;     // 20*1024*192 = 3,932,160
    float* xp0     = Bb + 10076160;    // 7,680
    float* xp1     = xp0 + 7680;       // 15,360
    float* xp2     = xp1 + 15360;      // 196,608
    float* hcat    = xp2 + 196608;     // 768
    float* xp[3] = {xp0, xp1, xp2};

    hipMemsetAsync(adjT, 0, (size_t)NPAD * NPAD * sizeof(float), stream);
    adj_kernel<<<NN, 512, 0, stream>>>(fe, te, adjT);
    proj_kernel<<<dim3(64, NN), 256, 0, stream>>>(x, ipW, ipb, A);

    // layer 1: A -> Bb (agg+residual), then h+LN in-place on Bb
    agg_mfma_kernel<<<dim3(512, 4), 256, 0, stream>>>(A, adjT, Bb);
    hln_kernel<<<dim3(64, NN), 256, 0, stream>>>(Bb, glW, glb, glg, glbe);
    // layer 2: Bb -> A, then in-place on A
    agg_mfma_kernel<<<dim3(512, 4), 256, 0, stream>>>(Bb, adjT, A);
    hln_kernel<<<dim3(64, NN), 256, 0, stream>>>(A, glW + 4096, glb + 64, glg + 64, glbe + 64);

    const int Trows[3] = {10, 20, 256};
    const int toff[3]  = {246, 236, 0};
    const int Mg[3]    = {40, 80, 1024};
    for (int gi = 0; gi < 3; ++gi) {
        transpose_kernel<<<dim3(1000, 6), dim3(32, 8), 0, stream>>>(Wih[gi], WihT);
        int mt = (Mg[gi] + 63) / 64;
        gru_pre_kernel<<<dim3(mt, KS_GRU), 256, 0, stream>>>(A, WihT, partial,
                                                             Trows[gi], toff[gi], Mg[gi]);
        gru_reduce_kernel<<<Mg[gi], 192, 0, stream>>>(partial, bih[gi], xp[gi], Mg[gi]);
    }
    gru_scan_kernel<<<3, 768, 0, stream>>>(xp[0], xp[1], xp[2],
                                           Whh[0], Whh[1], Whh[2],
                                           bhh[0], bhh[1], bhh[2], hcat);
    head_kernel<<<1, 512, 0, stream>>>(hcat, W1, b1, W2, b2, out);
}

// Round 6
// 1660.577 us; speedup vs baseline: 3.2085x; 1.3643x over previous
//
#include <hip/hip_runtime.h>
#include <math.h>

#define NN 500
#define DD 64
#define NPAD 512             // adjT padded to [512][512]
#define COLS 65536           // 1024 * 64
#define BS_TOT 1024          // B*S
#define I_DIM 32000          // N*D
#define KS_GRU 20            // K-split for GRU pre-GEMM
#define KSL 1600             // 32000/20

typedef __attribute__((ext_vector_type(8))) short bf16x8;
typedef __attribute__((ext_vector_type(4))) float f32x4;

__device__ __forceinline__ float gelu_f(float x) {
    return 0.5f * x * (1.0f + erff(x * 0.70710678118654752440f));
}

__device__ __forceinline__ unsigned short bf16_rn(float x) {
    unsigned int u = __float_as_uint(x);
    unsigned int r = u + 0x7FFFu + ((u >> 16) & 1u);
    return (unsigned short)(r >> 16);
}
__device__ __forceinline__ float bf16_tof(unsigned short h) {
    return __uint_as_float(((unsigned int)h) << 16);
}

// ---------------------------------------------------------------- adjacency
__global__ __launch_bounds__(512)
void adj_kernel(const float* __restrict__ fe, const float* __restrict__ te,
                float* __restrict__ adjT)
{
    __shared__ float fr[32];
    __shared__ float red[8];
    __shared__ float red2[8];
    const int n = blockIdx.x;
    const int tid = threadIdx.x;
    if (tid < 32) fr[tid] = fe[n * 32 + tid];
    __syncthreads();
    const int m = tid;
    float s = -1e30f;
    if (m < NN) {
        float acc = 0.f;
        #pragma unroll
        for (int f = 0; f < 32; ++f) acc += fr[f] * te[m * 32 + f];
        s = acc * 2.0f;   // 1/TEMP
    }
    float v = s;
    #pragma unroll
    for (int off = 32; off; off >>= 1) v = fmaxf(v, __shfl_xor(v, off));
    if ((tid & 63) == 0) red[tid >> 6] = v;
    __syncthreads();
    float bmax = red[0];
    #pragma unroll
    for (int i = 1; i < 8; ++i) bmax = fmaxf(bmax, red[i]);
    float e = (m < NN) ? expf(s - bmax) : 0.f;
    float v2 = e;
    #pragma unroll
    for (int off = 32; off; off >>= 1) v2 += __shfl_xor(v2, off);
    if ((tid & 63) == 0) red2[tid >> 6] = v2;
    __syncthreads();
    float bsum = 0.f;
    #pragma unroll
    for (int i = 0; i < 8; ++i) bsum += red2[i];
    if (m < NN) adjT[(size_t)m * NPAD + n] = e / bsum;
}

// ---------------------------------------------------------------- input proj
__global__ __launch_bounds__(256)
void proj_kernel(const float* __restrict__ xin, const float* __restrict__ ipW,
                 const float* __restrict__ ipb, float* __restrict__ Xp)
{
    __shared__ float wT[32][64];   // [f][d]
    __shared__ float xr[16][32];
    const int tid = threadIdx.x;
    const int n = blockIdx.y;
    const int bs0 = blockIdx.x * 16;
    for (int idx = tid; idx < 2048; idx += 256) {
        int d = idx >> 5, f = idx & 31;
        wT[f][d] = ipW[idx];
    }
    if (tid < 128) {
        int r = tid >> 3, fq = tid & 7;
        float4 v = *(const float4*)&xin[((size_t)(bs0 + r) * NN + n) * 32 + fq * 4];
        *(float4*)&xr[r][fq * 4] = v;
    }
    __syncthreads();
    const int lane = tid & 63, wv = tid >> 6;
    #pragma unroll
    for (int q = 0; q < 4; ++q) {
        int r = wv * 4 + q;
        float acc = ipb[lane];
        #pragma unroll
        for (int f = 0; f < 32; ++f) acc += xr[r][f] * wT[f][lane];
        Xp[((size_t)n * BS_TOT + bs0 + r) * 64 + lane] = gelu_f(acc);
    }
}

// ---------------------------------------------------------------- agg GEMM (split-bf16 MFMA)
__device__ __forceinline__ int swz_k(int row, int kbyte) {
    return kbyte ^ (((row >> 3) & 3) << 4);
}

__global__ __launch_bounds__(256)
void agg_mfma_kernel(const float* __restrict__ Xin, const float* __restrict__ adjT,
                     float* __restrict__ Cout)
{
    __shared__ short Ah[128 * 40];
    __shared__ short Al[128 * 40];
    __shared__ short Bh[128 * 40];
    __shared__ short Bl[128 * 40];

    const int tid  = threadIdx.x;
    const int lane = tid & 63;
    const int wave = tid >> 6;
    const int wm = (wave >> 1) * 64;
    const int wc = (wave & 1) * 64;
    const int q = lane >> 4, r16 = lane & 15;
    const int c0 = blockIdx.x * 128;
    const int m0 = blockIdx.y * 128;

    const int sa_m = tid >> 1, sa_kh = tid & 1;
    const int sb_c = tid & 127, sb_kh = tid >> 7;

    f32x4 acc[4][4];
    #pragma unroll
    for (int i = 0; i < 4; ++i)
        #pragma unroll
        for (int j = 0; j < 4; ++j) acc[i][j] = (f32x4){0.f, 0.f, 0.f, 0.f};

    for (int kc = 0; kc < 16; ++kc) {
        const int k0 = kc * 32;
        {
            const float* src = &adjT[(size_t)(m0 + sa_m) * NPAD + k0 + sa_kh * 16];
            char* rowH = (char*)Ah + sa_m * 80;
            char* rowL = (char*)Al + sa_m * 80;
            #pragma unroll
            for (int qd = 0; qd < 4; ++qd) {
                float4 v = ((const float4*)src)[qd];
                short4 h4, l4;
                h4.x = (short)bf16_rn(v.x); l4.x = (short)bf16_rn(v.x - bf16_tof(h4.x));
                h4.y = (short)bf16_rn(v.y); l4.y = (short)bf16_rn(v.y - bf16_tof(h4.y));
                h4.z = (short)bf16_rn(v.z); l4.z = (short)bf16_rn(v.z - bf16_tof(h4.z));
                h4.w = (short)bf16_rn(v.w); l4.w = (short)bf16_rn(v.w - bf16_tof(h4.w));
                int kb = swz_k(sa_m, sa_kh * 32 + qd * 8);
                *(short4*)(rowH + kb) = h4;
                *(short4*)(rowL + kb) = l4;
            }
        }
        {
            const size_t cb = (size_t)(c0 + sb_c);
            char* rowH = (char*)Bh + sb_c * 80;
            char* rowL = (char*)Bl + sb_c * 80;
            #pragma unroll
            for (int qd = 0; qd < 4; ++qd) {
                float xv[4];
                #pragma unroll
                for (int e = 0; e < 4; ++e) {
                    int kk = k0 + sb_kh * 16 + qd * 4 + e;
                    xv[e] = (kk < NN) ? Xin[(size_t)kk * COLS + cb] : 0.f;
                }
                short4 h4, l4;
                h4.x = (short)bf16_rn(xv[0]); l4.x = (short)bf16_rn(xv[0] - bf16_tof(h4.x));
                h4.y = (short)bf16_rn(xv[1]); l4.y = (short)bf16_rn(xv[1] - bf16_tof(h4.y));
                h4.z = (short)bf16_rn(xv[2]); l4.z = (short)bf16_rn(xv[2] - bf16_tof(h4.z));
                h4.w = (short)bf16_rn(xv[3]); l4.w = (short)bf16_rn(xv[3] - bf16_tof(h4.w));
                int kb = swz_k(sb_c, sb_kh * 32 + qd * 8);
                *(short4*)(rowH + kb) = h4;
                *(short4*)(rowL + kb) = l4;
            }
        }
        __syncthreads();
        bf16x8 ah[4], al[4];
        #pragma unroll
        for (int mi = 0; mi < 4; ++mi) {
            int row = wm + mi * 16 + r16;
            int kb = swz_k(row, q * 16);
            ah[mi] = *(const bf16x8*)((const char*)Ah + row * 80 + kb);
            al[mi] = *(const bf16x8*)((const char*)Al + row * 80 + kb);
        }
        #pragma unroll
        for (int ci = 0; ci < 4; ++ci) {
            int row = wc + ci * 16 + r16;
            int kb = swz_k(row, q * 16);
            bf16x8 bh = *(const bf16x8*)((const char*)Bh + row * 80 + kb);
            bf16x8 bl = *(const bf16x8*)((const char*)Bl + row * 80 + kb);
            #pragma unroll
            for (int mi = 0; mi < 4; ++mi) {
                acc[mi][ci] = __builtin_amdgcn_mfma_f32_16x16x32_bf16(ah[mi], bh, acc[mi][ci], 0, 0, 0);
                acc[mi][ci] = __builtin_amdgcn_mfma_f32_16x16x32_bf16(ah[mi], bl, acc[mi][ci], 0, 0, 0);
                acc[mi][ci] = __builtin_amdgcn_mfma_f32_16x16x32_bf16(al[mi], bh, acc[mi][ci], 0, 0, 0);
            }
        }
        __syncthreads();
    }
    #pragma unroll
    for (int mi = 0; mi < 4; ++mi) {
        #pragma unroll
        for (int r = 0; r < 4; ++r) {
            int m = m0 + wm + mi * 16 + q * 4 + r;
            if (m < NN) {
                #pragma unroll
                for (int ci = 0; ci < 4; ++ci) {
                    size_t idx = (size_t)m * COLS + c0 + wc + ci * 16 + r16;
                    Cout[idx] = acc[mi][ci][r] + Xin[idx];
                }
            }
        }
    }
}

// ---------------------------------------------------------------- h + LN (in-place)
__global__ __launch_bounds__(256)
void hln_kernel(float* __restrict__ Xio, const float* __restrict__ glW,
                const float* __restrict__ glb, const float* __restrict__ glg,
                const float* __restrict__ glbe)
{
    __shared__ float Wt[64][65];   // [d][e]
    __shared__ float ts[16][64];
    __shared__ float bB[64], bG[64], bE[64];
    const int tid = threadIdx.x;
    const int n = blockIdx.y;
    const int bs0 = blockIdx.x * 16;
    #pragma unroll
    for (int l = 0; l < 4; ++l) {
        int idx = tid + l * 256;       // = e*16 + dq
        int e = idx >> 4, dq = idx & 15;
        float4 v = *(const float4*)&glW[e * 64 + dq * 4];
        Wt[dq * 4 + 0][e] = v.x; Wt[dq * 4 + 1][e] = v.y;
        Wt[dq * 4 + 2][e] = v.z; Wt[dq * 4 + 3][e] = v.w;
    }
    if (tid < 64) { bB[tid] = glb[tid]; bG[tid] = glg[tid]; bE[tid] = glbe[tid]; }
    {
        int r = tid >> 4, dq = tid & 15;
        float4 v = *(const float4*)&Xio[((size_t)n * BS_TOT + bs0 + r) * 64 + dq * 4];
        *(float4*)&ts[r][dq * 4] = v;
    }
    __syncthreads();
    const int lane = tid & 63, wv = tid >> 6;
    #pragma unroll
    for (int q = 0; q < 4; ++q) {
        int r = wv * 4 + q;
        float acc = bB[lane];
        #pragma unroll
        for (int d = 0; d < 64; ++d) acc += ts[r][d] * Wt[d][lane];
        float h = gelu_f(acc);
        float s1 = h;
        #pragma unroll
        for (int off = 32; off; off >>= 1) s1 += __shfl_xor(s1, off);
        float mu = s1 * (1.f / 64.f);
        float dc = h - mu;
        float s2 = dc * dc;
        #pragma unroll
        for (int off = 32; off; off >>= 1) s2 += __shfl_xor(s2, off);
        float var = s2 * (1.f / 64.f);
        float y = dc * (1.f / sqrtf(var + 1e-5f)) * bG[lane] + bE[lane];
        Xio[((size_t)n * BS_TOT + bs0 + r) * 64 + lane] = y;
    }
}

// ---------------------------------------------------------------- Wih transpose (all 3 fused)
__global__ __launch_bounds__(256)
void transpose3_kernel(const float* __restrict__ W0, const float* __restrict__ W1,
                       const float* __restrict__ W2,
                       float* __restrict__ T0, float* __restrict__ T1, float* __restrict__ T2)
{
    __shared__ float t[32][33];
    const int gi = blockIdx.z;
    const float* A = (gi == 0) ? W0 : (gi == 1) ? W1 : W2;
    float* B = (gi == 0) ? T0 : (gi == 1) ? T1 : T2;
    const int i0 = blockIdx.x * 32;
    const int g0 = blockIdx.y * 32;
    const int tx = threadIdx.x, ty = threadIdx.y;
    #pragma unroll
    for (int k = 0; k < 4; ++k)
        t[ty + k * 8][tx] = A[(size_t)(g0 + ty + k * 8) * I_DIM + i0 + tx];
    __syncthreads();
    #pragma unroll
    for (int k = 0; k < 4; ++k)
        B[(size_t)(i0 + ty + k * 8) * 192 + g0 + tx] = t[tx][ty + k * 8];
}

// ---------------------------------------------------------------- GRU pre-GEMM (all 3 fused)
// blocks: [0,20)=s ks; [20,60)=m (mtid,ks); [60,380)=l (mtid,ks)
__global__ __launch_bounds__(256)
void gru_pre_fused_kernel(const float* __restrict__ Xp,
                          const float* __restrict__ T0, const float* __restrict__ T1,
                          const float* __restrict__ T2,
                          float* __restrict__ p0, float* __restrict__ p1,
                          float* __restrict__ p2)
{
    __shared__ float As[16][68];    // [k][r]
    __shared__ float Bs[16][192];   // [k][g]
    const int bid = blockIdx.x;
    int gi, mtid, ks;
    if (bid < 20)      { gi = 0; mtid = 0;              ks = bid; }
    else if (bid < 60) { int r = bid - 20; gi = 1; mtid = r & 1;  ks = r >> 1; }
    else               { int r = bid - 60; gi = 2; mtid = r & 15; ks = r >> 4; }
    const float* WihT = (gi == 0) ? T0 : (gi == 1) ? T1 : T2;
    float* partial    = (gi == 0) ? p0 : (gi == 1) ? p1 : p2;
    const int Trows   = (gi == 0) ? 10 : (gi == 1) ? 20 : 256;
    const int toff    = (gi == 0) ? 246 : (gi == 1) ? 236 : 0;
    const int M       = (gi == 0) ? 40 : (gi == 1) ? 80 : 1024;
    const int R0 = mtid * 64;

    const int tid = threadIdx.x;
    const int tx = tid & 15, ty = tid >> 4;
    const int rs = tid >> 2, dqs = tid & 3;
    const int Rr = R0 + rs;
    const bool vld = (Rr < M);
    int bt = 0;
    if (vld) { int b = Rr / Trows, t = Rr - b * Trows; bt = b * 256 + toff + t; }
    int bk[3], bg[3];
    #pragma unroll
    for (int l = 0; l < 3; ++l) { int idx = tid + l * 256; bk[l] = idx / 48; bg[l] = idx % 48; }

    float acc[4][12];
    #pragma unroll
    for (int i = 0; i < 4; ++i)
        #pragma unroll
        for (int j = 0; j < 12; ++j) acc[i][j] = 0.f;

    for (int c = 0; c < KSL / 16; ++c) {
        const int k0 = ks * KSL + c * 16;
        const int nn = k0 >> 6, d0 = k0 & 63;
        float4 v = make_float4(0.f, 0.f, 0.f, 0.f);
        if (vld) v = *(const float4*)&Xp[((size_t)nn * BS_TOT + bt) * 64 + d0 + dqs * 4];
        As[dqs * 4 + 0][rs] = v.x; As[dqs * 4 + 1][rs] = v.y;
        As[dqs * 4 + 2][rs] = v.z; As[dqs * 4 + 3][rs] = v.w;
        #pragma unroll
        for (int l = 0; l < 3; ++l) {
            float4 w = *(const float4*)&WihT[(size_t)(k0 + bk[l]) * 192 + bg[l] * 4];
            *(float4*)&Bs[bk[l]][bg[l] * 4] = w;
        }
        __syncthreads();
        #pragma unroll
        for (int k = 0; k < 16; ++k) {
            float a[4], b[12];
            *(float4*)&a[0] = *(const float4*)&As[k][ty * 4];
            *(float4*)&b[0] = *(const float4*)&Bs[k][tx * 12];
            *(float4*)&b[4] = *(const float4*)&Bs[k][tx * 12 + 4];
            *(float4*)&b[8] = *(const float4*)&Bs[k][tx * 12 + 8];
            #pragma unroll
            for (int i = 0; i < 4; ++i)
                #pragma unroll
                for (int j = 0; j < 12; ++j) acc[i][j] += a[i] * b[j];
        }
        __syncthreads();
    }
    #pragma unroll
    for (int i = 0; i < 4; ++i) {
        int R = R0 + ty * 4 + i;
        if (R < M) {
            #pragma unroll
            for (int j4 = 0; j4 < 3; ++j4)
                *(float4*)&partial[((size_t)ks * M + R) * 192 + tx * 12 + j4 * 4] =
                    *(float4*)&acc[i][j4 * 4];
        }
    }
}

// ---------------------------------------------------------------- reduce (all 3 fused)
__global__ __launch_bounds__(192)
void gru_reduce_fused_kernel(const float* __restrict__ p0, const float* __restrict__ p1,
                             const float* __restrict__ p2,
                             const float* __restrict__ bih0, const float* __restrict__ bih1,
                             const float* __restrict__ bih2,
                             float* __restrict__ xp0, float* __restrict__ xp1,
                             float* __restrict__ xp2)
{
    int r = blockIdx.x;
    const float* partial; const float* bih; float* xp; int M;
    if (r < 40)       { partial = p0; bih = bih0; xp = xp0; M = 40; }
    else if (r < 120) { r -= 40;  partial = p1; bih = bih1; xp = xp1; M = 80; }
    else              { r -= 120; partial = p2; bih = bih2; xp = xp2; M = 1024; }
    const int g = threadIdx.x;
    float acc = bih[g];
    for (int ks = 0; ks < KS_GRU; ++ks)
        acc += partial[((size_t)ks * M + r) * 192 + g];
    xp[(size_t)r * 192 + g] = acc;
}

// ---------------------------------------------------------------- GRU scan
// 12 blocks = (g3, b); 192 threads; Whh row per thread in VGPRs; xp prefetch.
__global__ __launch_bounds__(192)
void gru_scan_kernel(const float* __restrict__ xp_s, const float* __restrict__ xp_m,
                     const float* __restrict__ xp_l,
                     const float* __restrict__ Whh_s, const float* __restrict__ Whh_m,
                     const float* __restrict__ Whh_l,
                     const float* __restrict__ bhh_s, const float* __restrict__ bhh_m,
                     const float* __restrict__ bhh_l,
                     float* __restrict__ hcat)
{
    __shared__ float h[64];
    __shared__ float gh[192];
    const int blk = blockIdx.x;
    const int g3 = blk >> 2, b = blk & 3;
    const float* xp  = (g3 == 0) ? xp_s : (g3 == 1) ? xp_m : xp_l;
    const float* Whh = (g3 == 0) ? Whh_s : (g3 == 1) ? Whh_m : Whh_l;
    const float* bhh = (g3 == 0) ? bhh_s : (g3 == 1) ? bhh_m : bhh_l;
    const int T = (g3 == 0) ? 10 : (g3 == 1) ? 20 : 256;
    const int g = threadIdx.x;

    float w[64];
    #pragma unroll
    for (int k4 = 0; k4 < 16; ++k4) {
        float4 v = *(const float4*)&Whh[g * 64 + k4 * 4];
        w[k4 * 4 + 0] = v.x; w[k4 * 4 + 1] = v.y;
        w[k4 * 4 + 2] = v.z; w[k4 * 4 + 3] = v.w;
    }
    const float bh = bhh[g];
    if (g < 64) h[g] = 0.f;

    const float* xpb = xp + (size_t)b * T * 192;
    float xr_c = 0.f, xz_c = 0.f, xn_c = 0.f;
    if (g < 64) { xr_c = xpb[g]; xz_c = xpb[64 + g]; xn_c = xpb[128 + g]; }
    __syncthreads();

    for (int t = 0; t < T; ++t) {
        // prefetch next step's xp row (hidden under the matvec)
        float xr_n = 0.f, xz_n = 0.f, xn_n = 0.f;
        if (t + 1 < T && g < 64) {
            const float* xq = xpb + (size_t)(t + 1) * 192;
            xr_n = xq[g]; xz_n = xq[64 + g]; xn_n = xq[128 + g];
        }
        float a0 = 0.f, a1 = 0.f, a2 = 0.f, a3 = 0.f;
        #pragma unroll
        for (int k4 = 0; k4 < 16; ++k4) {
            float4 hv = ((const float4*)h)[k4];
            a0 += hv.x * w[k4 * 4 + 0];
            a1 += hv.y * w[k4 * 4 + 1];
            a2 += hv.z * w[k4 * 4 + 2];
            a3 += hv.w * w[k4 * 4 + 3];
        }
        gh[g] = bh + ((a0 + a1) + (a2 + a3));
        __syncthreads();
        if (g < 64) {
            float hr = gh[g], hz = gh[64 + g], hn = gh[128 + g];
            float r = 1.f / (1.f + __expf(-(xr_c + hr)));
            float z = 1.f / (1.f + __expf(-(xz_c + hz)));
            float pre = xn_c + r * hn;
            float e2 = __expf(2.f * pre);
            float nv = 1.f - 2.f / (e2 + 1.f);   // tanh
            h[g] = (1.f - z) * nv + z * h[g];
        }
        __syncthreads();
        xr_c = xr_n; xz_c = xz_n; xn_c = xn_n;
    }
    if (g < 64) hcat[b * 192 + g3 * 64 + g] = h[g];
}

// ---------------------------------------------------------------- head
__global__ __launch_bounds__(512)
void head_kernel(const float* __restrict__ hcat,
                 const float* __restrict__ W1, const float* __restrict__ b1,
                 const float* __restrict__ W2, const float* __restrict__ b2,
                 float* __restrict__ out)
{
    __shared__ float hc[4][192];
    __shared__ float h1[4][64];
    const int tid = threadIdx.x;
    for (int i = tid; i < 768; i += 512) hc[i / 192][i % 192] = hcat[i];
    __syncthreads();
    if (tid < 256) {
        int b = tid >> 6, e = tid & 63;
        float acc = b1[e];
        #pragma unroll
        for (int k = 0; k < 192; ++k) acc += hc[b][k] * W1[e * 192 + k];
        h1[b][e] = gelu_f(acc);
    }
    __syncthreads();
    for (int o = tid; o < 2000; o += 512) {
        int b = o / 500, n = o % 500;
        float acc = b2[n];
        #pragma unroll
        for (int k = 0; k < 64; ++k) acc += h1[b][k] * W2[n * 64 + k];
        out[o] = acc;
    }
}

// ================================================================ launch
extern "C" void kernel_launch(void* const* d_in, const int* in_sizes, int n_in,
                              void* d_out, int out_size, void* d_ws, size_t ws_size,
                              hipStream_t stream)
{
    (void)in_sizes; (void)n_in; (void)out_size; (void)ws_size;
    const float* x    = (const float*)d_in[0];
    const float* ipW  = (const float*)d_in[1];
    const float* ipb  = (const float*)d_in[2];
    const float* fe   = (const float*)d_in[3];
    const float* te   = (const float*)d_in[4];
    const float* glW  = (const float*)d_in[5];
    const float* glb  = (const float*)d_in[6];
    const float* glg  = (const float*)d_in[7];
    const float* glbe = (const float*)d_in[8];
    const float* Wih[3] = {(const float*)d_in[9],  (const float*)d_in[13], (const float*)d_in[17]};
    const float* Whh[3] = {(const float*)d_in[10], (const float*)d_in[14], (const float*)d_in[18]};
    const float* bih[3] = {(const float*)d_in[11], (const float*)d_in[15], (const float*)d_in[19]};
    const float* bhh[3] = {(const float*)d_in[12], (const float*)d_in[16], (const float*)d_in[20]};
    const float* W1 = (const float*)d_in[21];
    const float* b1 = (const float*)d_in[22];
    const float* W2 = (const float*)d_in[23];
    const float* b2 = (const float*)d_in[24];
    float* out = (float*)d_out;

    float* ws   = (float*)d_ws;
    float* A    = ws;                  // 32,768,000  (500*65536)  X ping
    float* Bb   = A + 32768000;        // 32,768,000              X pong
    float* adjT = Bb + 32768000;       // 262,144 (512*512)
    // GRU-phase scratch overlays Bb (dead after layer-2 GEMM):
    float* WihT0 = Bb;                         // 6,144,000 each
    float* WihT1 = WihT0 + 6144000;
    float* WihT2 = WihT1 + 6144000;
    float* part0 = WihT2 + 6144000;            // 20*40*192   = 153,600
    float* part1 = part0 + 153600;             // 20*80*192   = 307,200
    float* part2 = part1 + 307200;             // 20*1024*192 = 3,932,160
    float* xp0   = part2 + 3932160;            // 7,680
    float* xp1   = xp0 + 7680;                 // 15,360
    float* xp2   = xp1 + 15360;                // 196,608
    float* hcat  = xp2 + 196608;               // 768

    hipMemsetAsync(adjT, 0, (size_t)NPAD * NPAD * sizeof(float), stream);
    adj_kernel<<<NN, 512, 0, stream>>>(fe, te, adjT);
    proj_kernel<<<dim3(64, NN), 256, 0, stream>>>(x, ipW, ipb, A);

    // layer 1: A -> Bb (agg+residual), then h+LN in-place on Bb
    agg_mfma_kernel<<<dim3(512, 4), 256, 0, stream>>>(A, adjT, Bb);
    hln_kernel<<<dim3(64, NN), 256, 0, stream>>>(Bb, glW, glb, glg, glbe);
    // layer 2: Bb -> A, then in-place on A
    agg_mfma_kernel<<<dim3(512, 4), 256, 0, stream>>>(Bb, adjT, A);
    hln_kernel<<<dim3(64, NN), 256, 0, stream>>>(A, glW + 4096, glb + 64, glg + 64, glbe + 64);

    transpose3_kernel<<<dim3(1000, 6, 3), dim3(32, 8), 0, stream>>>(
        Wih[0], Wih[1], Wih[2], WihT0, WihT1, WihT2);
    gru_pre_fused_kernel<<<380, 256, 0, stream>>>(A, WihT0, WihT1, WihT2,
                                                  part0, part1, part2);
    gru_reduce_fused_kernel<<<1144, 192, 0, stream>>>(part0, part1, part2,
                                                      bih[0], bih[1], bih[2],
                                                      xp0, xp1, xp2);
    gru_scan_kernel<<<12, 192, 0, stream>>>(xp0, xp1, xp2,
                                            Whh[0], Whh[1], Whh[2],
                                            bhh[0], bhh[1], bhh[2], hcat);
    head_kernel<<<1, 512, 0, stream>>>(hcat, W1, b1, W2, b2, out);
}

// Round 7
// 1458.289 us; speedup vs baseline: 3.6536x; 1.1387x over previous
//
#include <hip/hip_runtime.h>
#include <math.h>

#define NN 500
#define DD 64
#define NPAD 512             // adjT padded to [512][512]
#define COLS 65536           // 1024 * 64
#define BS_TOT 1024          // B*S
#define I_DIM 32000          // N*D
#define KS_GRU 40            // K-split for GRU pre-GEMM
#define KSL 800              // 32000/40

typedef __attribute__((ext_vector_type(8))) short bf16x8;
typedef __attribute__((ext_vector_type(4))) float f32x4;

__device__ __forceinline__ float gelu_f(float x) {
    return 0.5f * x * (1.0f + erff(x * 0.70710678118654752440f));
}

__device__ __forceinline__ unsigned short bf16_rn(float x) {
    unsigned int u = __float_as_uint(x);
    unsigned int r = u + 0x7FFFu + ((u >> 16) & 1u);
    return (unsigned short)(r >> 16);
}
__device__ __forceinline__ float bf16_tof(unsigned short h) {
    return __uint_as_float(((unsigned int)h) << 16);
}

// LDS XOR swizzle (16B granularity within 64B k-extent)
__device__ __forceinline__ int swz_k(int row, int kbyte) {
    return kbyte ^ (((row >> 3) & 3) << 4);
}

// ---------------------------------------------------------------- adjacency
// writes split-bf16: adjTh/adjTl [m][n], identical values to the old
// in-kernel conversion (agg staged bf16_rn(fp32) anyway).
__global__ __launch_bounds__(512)
void adj_kernel(const float* __restrict__ fe, const float* __restrict__ te,
                short* __restrict__ adjTh, short* __restrict__ adjTl)
{
    __shared__ float fr[32];
    __shared__ float red[8];
    __shared__ float red2[8];
    const int n = blockIdx.x;
    const int tid = threadIdx.x;
    if (tid < 32) fr[tid] = fe[n * 32 + tid];
    __syncthreads();
    const int m = tid;
    float s = -1e30f;
    if (m < NN) {
        float acc = 0.f;
        #pragma unroll
        for (int f = 0; f < 32; ++f) acc += fr[f] * te[m * 32 + f];
        s = acc * 2.0f;   // 1/TEMP
    }
    float v = s;
    #pragma unroll
    for (int off = 32; off; off >>= 1) v = fmaxf(v, __shfl_xor(v, off));
    if ((tid & 63) == 0) red[tid >> 6] = v;
    __syncthreads();
    float bmax = red[0];
    #pragma unroll
    for (int i = 1; i < 8; ++i) bmax = fmaxf(bmax, red[i]);
    float e = (m < NN) ? expf(s - bmax) : 0.f;
    float v2 = e;
    #pragma unroll
    for (int off = 32; off; off >>= 1) v2 += __shfl_xor(v2, off);
    if ((tid & 63) == 0) red2[tid >> 6] = v2;
    __syncthreads();
    float bsum = 0.f;
    #pragma unroll
    for (int i = 0; i < 8; ++i) bsum += red2[i];
    if (m < NN) {
        float p = e / bsum;
        unsigned short h = bf16_rn(p);
        adjTh[(size_t)m * NPAD + n] = (short)h;
        adjTl[(size_t)m * NPAD + n] = (short)bf16_rn(p - bf16_tof(h));
    }
}

// ---------------------------------------------------------------- input proj
__global__ __launch_bounds__(256)
void proj_kernel(const float* __restrict__ xin, const float* __restrict__ ipW,
                 const float* __restrict__ ipb, float* __restrict__ Xp)
{
    __shared__ float wT[32][64];   // [f][d]
    __shared__ float xr[16][32];
    const int tid = threadIdx.x;
    const int n = blockIdx.y;
    const int bs0 = blockIdx.x * 16;
    for (int idx = tid; idx < 2048; idx += 256) {
        int d = idx >> 5, f = idx & 31;
        wT[f][d] = ipW[idx];
    }
    if (tid < 128) {
        int r = tid >> 3, fq = tid & 7;
        float4 v = *(const float4*)&xin[((size_t)(bs0 + r) * NN + n) * 32 + fq * 4];
        *(float4*)&xr[r][fq * 4] = v;
    }
    __syncthreads();
    const int lane = tid & 63, wv = tid >> 6;
    #pragma unroll
    for (int q = 0; q < 4; ++q) {
        int r = wv * 4 + q;
        float acc = ipb[lane];
        #pragma unroll
        for (int f = 0; f < 32; ++f) acc += xr[r][f] * wT[f][lane];
        Xp[((size_t)n * BS_TOT + bs0 + r) * 64 + lane] = gelu_f(acc);
    }
}

// ---------------------------------------------------------------- agg GEMM (split-bf16 MFMA)
__global__ __launch_bounds__(256)
void agg_mfma_kernel(const float* __restrict__ Xin,
                     const short* __restrict__ adjTh, const short* __restrict__ adjTl,
                     float* __restrict__ Cout)
{
    __shared__ __align__(16) short Ah[128 * 40];
    __shared__ __align__(16) short Al[128 * 40];
    __shared__ __align__(16) short Bh[128 * 40];
    __shared__ __align__(16) short Bl[128 * 40];

    const int tid  = threadIdx.x;
    const int lane = tid & 63;
    const int wave = tid >> 6;
    const int wm = (wave >> 1) * 64;
    const int wc = (wave & 1) * 64;
    const int q = lane >> 4, r16 = lane & 15;
    const int c0 = blockIdx.x * 128;
    const int m0 = blockIdx.y * 128;

    const int sa_m = tid >> 1, sa_kh = tid & 1;
    const int sb_c = tid & 127, sb_kh = tid >> 7;

    f32x4 acc[4][4];
    #pragma unroll
    for (int i = 0; i < 4; ++i)
        #pragma unroll
        for (int j = 0; j < 4; ++j) acc[i][j] = (f32x4){0.f, 0.f, 0.f, 0.f};

    for (int kc = 0; kc < 16; ++kc) {
        const int k0 = kc * 32;
        // ---- stage A: pre-split bf16, pure copy
        {
            const size_t base = (size_t)(m0 + sa_m) * NPAD + k0 + sa_kh * 16;
            bf16x8 h0 = *(const bf16x8*)&adjTh[base];
            bf16x8 h1 = *(const bf16x8*)&adjTh[base + 8];
            bf16x8 l0 = *(const bf16x8*)&adjTl[base];
            bf16x8 l1 = *(const bf16x8*)&adjTl[base + 8];
            char* rowH = (char*)Ah + sa_m * 80;
            char* rowL = (char*)Al + sa_m * 80;
            *(bf16x8*)(rowH + swz_k(sa_m, sa_kh * 32))      = h0;
            *(bf16x8*)(rowH + swz_k(sa_m, sa_kh * 32 + 16)) = h1;
            *(bf16x8*)(rowL + swz_k(sa_m, sa_kh * 32))      = l0;
            *(bf16x8*)(rowL + swz_k(sa_m, sa_kh * 32 + 16)) = l1;
        }
        // ---- stage B transposed: Bt[c][k] (guard k >= 500 -> 0), fp32 split
        {
            const size_t cb = (size_t)(c0 + sb_c);
            char* rowH = (char*)Bh + sb_c * 80;
            char* rowL = (char*)Bl + sb_c * 80;
            #pragma unroll
            for (int qd = 0; qd < 4; ++qd) {
                float xv[4];
                #pragma unroll
                for (int e = 0; e < 4; ++e) {
                    int kk = k0 + sb_kh * 16 + qd * 4 + e;
                    xv[e] = (kk < NN) ? Xin[(size_t)kk * COLS + cb] : 0.f;
                }
                short4 h4, l4;
                h4.x = (short)bf16_rn(xv[0]); l4.x = (short)bf16_rn(xv[0] - bf16_tof(h4.x));
                h4.y = (short)bf16_rn(xv[1]); l4.y = (short)bf16_rn(xv[1] - bf16_tof(h4.y));
                h4.z = (short)bf16_rn(xv[2]); l4.z = (short)bf16_rn(xv[2] - bf16_tof(h4.z));
                h4.w = (short)bf16_rn(xv[3]); l4.w = (short)bf16_rn(xv[3] - bf16_tof(h4.w));
                int kb = swz_k(sb_c, sb_kh * 32 + qd * 8);
                *(short4*)(rowH + kb) = h4;
                *(short4*)(rowL + kb) = l4;
            }
        }
        __syncthreads();
        bf16x8 ah[4], al[4];
        #pragma unroll
        for (int mi = 0; mi < 4; ++mi) {
            int row = wm + mi * 16 + r16;
            int kb = swz_k(row, q * 16);
            ah[mi] = *(const bf16x8*)((const char*)Ah + row * 80 + kb);
            al[mi] = *(const bf16x8*)((const char*)Al + row * 80 + kb);
        }
        #pragma unroll
        for (int ci = 0; ci < 4; ++ci) {
            int row = wc + ci * 16 + r16;
            int kb = swz_k(row, q * 16);
            bf16x8 bh = *(const bf16x8*)((const char*)Bh + row * 80 + kb);
            bf16x8 bl = *(const bf16x8*)((const char*)Bl + row * 80 + kb);
            #pragma unroll
            for (int mi = 0; mi < 4; ++mi) {
                acc[mi][ci] = __builtin_amdgcn_mfma_f32_16x16x32_bf16(ah[mi], bh, acc[mi][ci], 0, 0, 0);
                acc[mi][ci] = __builtin_amdgcn_mfma_f32_16x16x32_bf16(ah[mi], bl, acc[mi][ci], 0, 0, 0);
                acc[mi][ci] = __builtin_amdgcn_mfma_f32_16x16x32_bf16(al[mi], bh, acc[mi][ci], 0, 0, 0);
            }
        }
        __syncthreads();
    }
    #pragma unroll
    for (int mi = 0; mi < 4; ++mi) {
        #pragma unroll
        for (int r = 0; r < 4; ++r) {
            int m = m0 + wm + mi * 16 + q * 4 + r;
            if (m < NN) {
                #pragma unroll
                for (int ci = 0; ci < 4; ++ci) {
                    size_t idx = (size_t)m * COLS + c0 + wc + ci * 16 + r16;
                    Cout[idx] = acc[mi][ci][r] + Xin[idx];
                }
            }
        }
    }
}

// ---------------------------------------------------------------- h + LN (in-place)
__global__ __launch_bounds__(256)
void hln_kernel(float* __restrict__ Xio, const float* __restrict__ glW,
                const float* __restrict__ glb, const float* __restrict__ glg,
                const float* __restrict__ glbe)
{
    __shared__ float Wt[64][65];   // [d][e]
    __shared__ float ts[16][64];
    __shared__ float bB[64], bG[64], bE[64];
    const int tid = threadIdx.x;
    const int n = blockIdx.y;
    const int bs0 = blockIdx.x * 16;
    #pragma unroll
    for (int l = 0; l < 4; ++l) {
        int idx = tid + l * 256;       // = e*16 + dq
        int e = idx >> 4, dq = idx & 15;
        float4 v = *(const float4*)&glW[e * 64 + dq * 4];
        Wt[dq * 4 + 0][e] = v.x; Wt[dq * 4 + 1][e] = v.y;
        Wt[dq * 4 + 2][e] = v.z; Wt[dq * 4 + 3][e] = v.w;
    }
    if (tid < 64) { bB[tid] = glb[tid]; bG[tid] = glg[tid]; bE[tid] = glbe[tid]; }
    {
        int r = tid >> 4, dq = tid & 15;
        float4 v = *(const float4*)&Xio[((size_t)n * BS_TOT + bs0 + r) * 64 + dq * 4];
        *(float4*)&ts[r][dq * 4] = v;
    }
    __syncthreads();
    const int lane = tid & 63, wv = tid >> 6;
    #pragma unroll
    for (int q = 0; q < 4; ++q) {
        int r = wv * 4 + q;
        float acc = bB[lane];
        #pragma unroll
        for (int d = 0; d < 64; ++d) acc += ts[r][d] * Wt[d][lane];
        float h = gelu_f(acc);
        float s1 = h;
        #pragma unroll
        for (int off = 32; off; off >>= 1) s1 += __shfl_xor(s1, off);
        float mu = s1 * (1.f / 64.f);
        float dc = h - mu;
        float s2 = dc * dc;
        #pragma unroll
        for (int off = 32; off; off >>= 1) s2 += __shfl_xor(s2, off);
        float var = s2 * (1.f / 64.f);
        float y = dc * (1.f / sqrtf(var + 1e-5f)) * bG[lane] + bE[lane];
        Xio[((size_t)n * BS_TOT + bs0 + r) * 64 + lane] = y;
    }
}

// ---------------------------------------------------------------- Wih split-convert
// Wih is natively [gate][k] == the MFMA B layout; no transpose, just split.
__global__ __launch_bounds__(256)
void wconv_kernel(const float* __restrict__ W0, const float* __restrict__ W1,
                  const float* __restrict__ W2,
                  short* __restrict__ h0, short* __restrict__ l0,
                  short* __restrict__ h1, short* __restrict__ l1,
                  short* __restrict__ h2, short* __restrict__ l2)
{
    const int gi = blockIdx.y;
    const float* W = (gi == 0) ? W0 : (gi == 1) ? W1 : W2;
    short* H = (gi == 0) ? h0 : (gi == 1) ? h1 : h2;
    short* L = (gi == 0) ? l0 : (gi == 1) ? l1 : l2;
    const size_t i = ((size_t)blockIdx.x * 256 + threadIdx.x) * 4;
    float4 v = *(const float4*)&W[i];
    short4 h4, l4;
    h4.x = (short)bf16_rn(v.x); l4.x = (short)bf16_rn(v.x - bf16_tof(h4.x));
    h4.y = (short)bf16_rn(v.y); l4.y = (short)bf16_rn(v.y - bf16_tof(h4.y));
    h4.z = (short)bf16_rn(v.z); l4.z = (short)bf16_rn(v.z - bf16_tof(h4.z));
    h4.w = (short)bf16_rn(v.w); l4.w = (short)bf16_rn(v.w - bf16_tof(h4.w));
    *(short4*)&H[i] = h4;
    *(short4*)&L[i] = l4;
}

// ---------------------------------------------------------------- GRU pre-GEMM (MFMA)
// partial[ks][R][g] = sum_{k in slice} xflat[R][k] * Wih[g][k]
// Tile M=64 x N=192, BK=32; 4 waves = 2(rows) x 2(gates) of 32x96.
// blocks: [0,40)=s ks; [40,120)=m (mtid,ks); [120,760)=l (mtid,ks)
__global__ __launch_bounds__(256)
void gru_pre_mfma_kernel(const float* __restrict__ Xp,
                         const short* __restrict__ Wh0, const short* __restrict__ Wl0,
                         const short* __restrict__ Wh1, const short* __restrict__ Wl1,
                         const short* __restrict__ Wh2, const short* __restrict__ Wl2,
                         float* __restrict__ p0, float* __restrict__ p1,
                         float* __restrict__ p2)
{
    __shared__ __align__(16) short Ah[64 * 40];
    __shared__ __align__(16) short Al[64 * 40];
    __shared__ __align__(16) short Bh[192 * 40];
    __shared__ __align__(16) short Bl[192 * 40];

    const int bid = blockIdx.x;
    int gi, mtid, ks;
    if (bid < 40)       { gi = 0; mtid = 0;             ks = bid; }
    else if (bid < 120) { int r = bid - 40;  gi = 1; mtid = r & 1;  ks = r >> 1; }
    else                { int r = bid - 120; gi = 2; mtid = r & 15; ks = r >> 4; }
    const short* Wh = (gi == 0) ? Wh0 : (gi == 1) ? Wh1 : Wh2;
    const short* Wl = (gi == 0) ? Wl0 : (gi == 1) ? Wl1 : Wl2;
    float* partial  = (gi == 0) ? p0 : (gi == 1) ? p1 : p2;
    const int Trows = (gi == 0) ? 10 : (gi == 1) ? 20 : 256;
    const int toff  = (gi == 0) ? 246 : (gi == 1) ? 236 : 0;
    const int M     = (gi == 0) ? 40 : (gi == 1) ? 80 : 1024;
    const int R0 = mtid * 64;

    const int tid  = threadIdx.x;
    const int lane = tid & 63;
    const int wave = tid >> 6;
    const int wr = (wave & 1) * 32;    // row sub-tile
    const int wg = (wave >> 1) * 96;   // gate sub-tile
    const int q = lane >> 4, r16 = lane & 15;

    // A staging map: 64 rows x 4 k-groups (8 k each)
    const int sa_r = tid >> 2, sa_kq = tid & 3;
    const bool vldA = (R0 + sa_r < M);
    int btA = 0;
    if (vldA) { int R = R0 + sa_r; int b = R / Trows, t = R - b * Trows; btA = b * 256 + toff + t; }

    f32x4 acc[2][6];
    #pragma unroll
    for (int i = 0; i < 2; ++i)
        #pragma unroll
        for (int j = 0; j < 6; ++j) acc[i][j] = (f32x4){0.f, 0.f, 0.f, 0.f};

    for (int c = 0; c < KSL / 32; ++c) {
        const int k0 = ks * KSL + c * 32;
        // ---- stage A (X fp32 -> split bf16). 8 consecutive k = 8 consecutive d.
        {
            const int kk = k0 + sa_kq * 8;
            const int nn = kk >> 6, d0 = kk & 63;
            float4 v0 = make_float4(0.f, 0.f, 0.f, 0.f), v1 = v0;
            if (vldA) {
                const float* src = &Xp[((size_t)nn * BS_TOT + btA) * 64 + d0];
                v0 = *(const float4*)src;
                v1 = *(const float4*)(src + 4);
            }
            short4 h0, l0, h1, l1;
            h0.x = (short)bf16_rn(v0.x); l0.x = (short)bf16_rn(v0.x - bf16_tof(h0.x));
            h0.y = (short)bf16_rn(v0.y); l0.y = (short)bf16_rn(v0.y - bf16_tof(h0.y));
            h0.z = (short)bf16_rn(v0.z); l0.z = (short)bf16_rn(v0.z - bf16_tof(h0.z));
            h0.w = (short)bf16_rn(v0.w); l0.w = (short)bf16_rn(v0.w - bf16_tof(h0.w));
            h1.x = (short)bf16_rn(v1.x); l1.x = (short)bf16_rn(v1.x - bf16_tof(h1.x));
            h1.y = (short)bf16_rn(v1.y); l1.y = (short)bf16_rn(v1.y - bf16_tof(h1.y));
            h1.z = (short)bf16_rn(v1.z); l1.z = (short)bf16_rn(v1.z - bf16_tof(h1.z));
            h1.w = (short)bf16_rn(v1.w); l1.w = (short)bf16_rn(v1.w - bf16_tof(h1.w));
            int kb = swz_k(sa_r, sa_kq * 16);
            char* rowH = (char*)Ah + sa_r * 80;
            char* rowL = (char*)Al + sa_r * 80;
            *(short4*)(rowH + kb) = h0; *(short4*)(rowH + kb + 8) = h1;
            *(short4*)(rowL + kb) = l0; *(short4*)(rowL + kb + 8) = l1;
        }
        // ---- stage B (pre-split bf16, [g][k] native): 768 items of 16B h + 16B l
        #pragma unroll
        for (int l = 0; l < 3; ++l) {
            int idx = tid + l * 256;
            int g = idx >> 2, kq = idx & 3;
            const size_t src = (size_t)g * I_DIM + k0 + kq * 8;
            bf16x8 hv = *(const bf16x8*)&Wh[src];
            bf16x8 lv = *(const bf16x8*)&Wl[src];
            int kb = swz_k(g, kq * 16);
            *(bf16x8*)((char*)Bh + g * 80 + kb) = hv;
            *(bf16x8*)((char*)Bl + g * 80 + kb) = lv;
        }
        __syncthreads();
        // ---- fragments + MFMA
        bf16x8 ah[2], al[2];
        #pragma unroll
        for (int mi = 0; mi < 2; ++mi) {
            int row = wr + mi * 16 + r16;
            int kb = swz_k(row, q * 16);
            ah[mi] = *(const bf16x8*)((const char*)Ah + row * 80 + kb);
            al[mi] = *(const bf16x8*)((const char*)Al + row * 80 + kb);
        }
        #pragma unroll
        for (int ci = 0; ci < 6; ++ci) {
            int grow = wg + ci * 16 + r16;
            int kb = swz_k(grow, q * 16);
            bf16x8 bh = *(const bf16x8*)((const char*)Bh + grow * 80 + kb);
            bf16x8 bl = *(const bf16x8*)((const char*)Bl + grow * 80 + kb);
            #pragma unroll
            for (int mi = 0; mi < 2; ++mi) {
                acc[mi][ci] = __builtin_amdgcn_mfma_f32_16x16x32_bf16(ah[mi], bh, acc[mi][ci], 0, 0, 0);
                acc[mi][ci] = __builtin_amdgcn_mfma_f32_16x16x32_bf16(ah[mi], bl, acc[mi][ci], 0, 0, 0);
                acc[mi][ci] = __builtin_amdgcn_mfma_f32_16x16x32_bf16(al[mi], bh, acc[mi][ci], 0, 0, 0);
            }
        }
        __syncthreads();
    }
    // ---- epilogue: D row = M-dim (rows), col = N-dim (gates)
    #pragma unroll
    for (int mi = 0; mi < 2; ++mi) {
        #pragma unroll
        for (int r = 0; r < 4; ++r) {
            int R = R0 + wr + mi * 16 + q * 4 + r;
            if (R < M) {
                #pragma unroll
                for (int ci = 0; ci < 6; ++ci)
                    partial[((size_t)ks * M + R) * 192 + wg + ci * 16 + r16] = acc[mi][ci][r];
            }
        }
    }
}

// ---------------------------------------------------------------- reduce (all 3 fused)
__global__ __launch_bounds__(192)
void gru_reduce_fused_kernel(const float* __restrict__ p0, const float* __restrict__ p1,
                             const float* __restrict__ p2,
                             const float* __restrict__ bih0, const float* __restrict__ bih1,
                             const float* __restrict__ bih2,
                             float* __restrict__ xp0, float* __restrict__ xp1,
                             float* __restrict__ xp2)
{
    int r = blockIdx.x;
    const float* partial; const float* bih; float* xp; int M;
    if (r < 40)       { partial = p0; bih = bih0; xp = xp0; M = 40; }
    else if (r < 120) { r -= 40;  partial = p1; bih = bih1; xp = xp1; M = 80; }
    else              { r -= 120; partial = p2; bih = bih2; xp = xp2; M = 1024; }
    const int g = threadIdx.x;
    float acc = bih[g];
    for (int ks = 0; ks < KS_GRU; ++ks)
        acc += partial[((size_t)ks * M + r) * 192 + g];
    xp[(size_t)r * 192 + g] = acc;
}

// ---------------------------------------------------------------- GRU scan
__global__ __launch_bounds__(192)
void gru_scan_kernel(const float* __restrict__ xp_s, const float* __restrict__ xp_m,
                     const float* __restrict__ xp_l,
                     const float* __restrict__ Whh_s, const float* __restrict__ Whh_m,
                     const float* __restrict__ Whh_l,
                     const float* __restrict__ bhh_s, const float* __restrict__ bhh_m,
                     const float* __restrict__ bhh_l,
                     float* __restrict__ hcat)
{
    __shared__ float h[64];
    __shared__ float gh[192];
    const int blk = blockIdx.x;
    const int g3 = blk >> 2, b = blk & 3;
    const float* xp  = (g3 == 0) ? xp_s : (g3 == 1) ? xp_m : xp_l;
    const float* Whh = (g3 == 0) ? Whh_s : (g3 == 1) ? Whh_m : Whh_l;
    const float* bhh = (g3 == 0) ? bhh_s : (g3 == 1) ? bhh_m : bhh_l;
    const int T = (g3 == 0) ? 10 : (g3 == 1) ? 20 : 256;
    const int g = threadIdx.x;

    float w[64];
    #pragma unroll
    for (int k4 = 0; k4 < 16; ++k4) {
        float4 v = *(const float4*)&Whh[g * 64 + k4 * 4];
        w[k4 * 4 + 0] = v.x; w[k4 * 4 + 1] = v.y;
        w[k4 * 4 + 2] = v.z; w[k4 * 4 + 3] = v.w;
    }
    const float bh = bhh[g];
    if (g < 64) h[g] = 0.f;

    const float* xpb = xp + (size_t)b * T * 192;
    float xr_c = 0.f, xz_c = 0.f, xn_c = 0.f;
    if (g < 64) { xr_c = xpb[g]; xz_c = xpb[64 + g]; xn_c = xpb[128 + g]; }
    __syncthreads();

    for (int t = 0; t < T; ++t) {
        float xr_n = 0.f, xz_n = 0.f, xn_n = 0.f;
        if (t + 1 < T && g < 64) {
            const float* xq = xpb + (size_t)(t + 1) * 192;
            xr_n = xq[g]; xz_n = xq[64 + g]; xn_n = xq[128 + g];
        }
        float a0 = 0.f, a1 = 0.f, a2 = 0.f, a3 = 0.f;
        #pragma unroll
        for (int k4 = 0; k4 < 16; ++k4) {
            float4 hv = ((const float4*)h)[k4];
            a0 += hv.x * w[k4 * 4 + 0];
            a1 += hv.y * w[k4 * 4 + 1];
            a2 += hv.z * w[k4 * 4 + 2];
            a3 += hv.w * w[k4 * 4 + 3];
        }
        gh[g] = bh + ((a0 + a1) + (a2 + a3));
        __syncthreads();
        if (g < 64) {
            float hr = gh[g], hz = gh[64 + g], hn = gh[128 + g];
            float r = 1.f / (1.f + __expf(-(xr_c + hr)));
            float z = 1.f / (1.f + __expf(-(xz_c + hz)));
            float pre = xn_c + r * hn;
            float e2 = __expf(2.f * pre);
            float nv = 1.f - 2.f / (e2 + 1.f);   // tanh
            h[g] = (1.f - z) * nv + z * h[g];
        }
        __syncthreads();
        xr_c = xr_n; xz_c = xz_n; xn_c = xn_n;
    }
    if (g < 64) hcat[b * 192 + g3 * 64 + g] = h[g];
}

// ---------------------------------------------------------------- head
__global__ __launch_bounds__(512)
void head_kernel(const float* __restrict__ hcat,
                 const float* __restrict__ W1, const float* __restrict__ b1,
                 const float* __restrict__ W2, const float* __restrict__ b2,
                 float* __restrict__ out)
{
    __shared__ float hc[4][192];
    __shared__ float h1[4][64];
    const int tid = threadIdx.x;
    for (int i = tid; i < 768; i += 512) hc[i / 192][i % 192] = hcat[i];
    __syncthreads();
    if (tid < 256) {
        int b = tid >> 6, e = tid & 63;
        float acc = b1[e];
        #pragma unroll
        for (int k = 0; k < 192; ++k) acc += hc[b][k] * W1[e * 192 + k];
        h1[b][e] = gelu_f(acc);
    }
    __syncthreads();
    for (int o = tid; o < 2000; o += 512) {
        int b = o / 500, n = o % 500;
        float acc = b2[n];
        #pragma unroll
        for (int k = 0; k < 64; ++k) acc += h1[b][k] * W2[n * 64 + k];
        out[o] = acc;
    }
}

// ================================================================ launch
extern "C" void kernel_launch(void* const* d_in, const int* in_sizes, int n_in,
                              void* d_out, int out_size, void* d_ws, size_t ws_size,
                              hipStream_t stream)
{
    (void)in_sizes; (void)n_in; (void)out_size; (void)ws_size;
    const float* x    = (const float*)d_in[0];
    const float* ipW  = (const float*)d_in[1];
    const float* ipb  = (const float*)d_in[2];
    const float* fe   = (const float*)d_in[3];
    const float* te   = (const float*)d_in[4];
    const float* glW  = (const float*)d_in[5];
    const float* glb  = (const float*)d_in[6];
    const float* glg  = (const float*)d_in[7];
    const float* glbe = (const float*)d_in[8];
    const float* Wih[3] = {(const float*)d_in[9],  (const float*)d_in[13], (const float*)d_in[17]};
    const float* Whh[3] = {(const float*)d_in[10], (const float*)d_in[14], (const float*)d_in[18]};
    const float* bih[3] = {(const float*)d_in[11], (const float*)d_in[15], (const float*)d_in[19]};
    const float* bhh[3] = {(const float*)d_in[12], (const float*)d_in[16], (const float*)d_in[20]};
    const float* W1 = (const float*)d_in[21];
    const float* b1 = (const float*)d_in[22];
    const float* W2 = (const float*)d_in[23];
    const float* b2 = (const float*)d_in[24];
    float* out = (float*)d_out;

    float* ws   = (float*)d_ws;
    float* A    = ws;                  // 32,768,000 floats (500*65536)  X ping
    float* Bb   = A + 32768000;        // 32,768,000 floats             X pong
    short* adjTh = (short*)(Bb + 32768000);    // 512*512 shorts
    short* adjTl = adjTh + NPAD * NPAD;        // 512*512 shorts
    // GRU-phase scratch overlays Bb (dead after layer-2 GEMM):
    short* wbase = (short*)Bb;
    short* Wh0 = wbase;                        // 6,144,000 shorts each
    short* Wl0 = Wh0 + 6144000;
    short* Wh1 = Wl0 + 6144000;
    short* Wl1 = Wh1 + 6144000;
    short* Wh2 = Wl1 + 6144000;
    short* Wl2 = Wh2 + 6144000;
    float* pbase = Bb + 18432000;
    float* part0 = pbase;                      // 40*40*192   = 307,200
    float* part1 = part0 + 307200;             // 40*80*192   = 614,400
    float* part2 = part1 + 614400;             // 40*1024*192 = 7,864,320
    float* xp0   = part2 + 7864320;            // 7,680
    float* xp1   = xp0 + 7680;                 // 15,360
    float* xp2   = xp1 + 15360;                // 196,608
    float* hcat  = xp2 + 196608;               // 768

    hipMemsetAsync(adjTh, 0, (size_t)NPAD * NPAD * 2 * sizeof(short), stream);
    adj_kernel<<<NN, 512, 0, stream>>>(fe, te, adjTh, adjTl);
    proj_kernel<<<dim3(64, NN), 256, 0, stream>>>(x, ipW, ipb, A);

    // layer 1: A -> Bb (agg+residual), then h+LN in-place on Bb
    agg_mfma_kernel<<<dim3(512, 4), 256, 0, stream>>>(A, adjTh, adjTl, Bb);
    hln_kernel<<<dim3(64, NN), 256, 0, stream>>>(Bb, glW, glb, glg, glbe);
    // layer 2: Bb -> A, then in-place on A
    agg_mfma_kernel<<<dim3(512, 4), 256, 0, stream>>>(Bb, adjTh, adjTl, A);
    hln_kernel<<<dim3(64, NN), 256, 0, stream>>>(A, glW + 4096, glb + 64, glg + 64, glbe + 64);

    wconv_kernel<<<dim3(6000, 3), 256, 0, stream>>>(Wih[0], Wih[1], Wih[2],
                                                    Wh0, Wl0, Wh1, Wl1, Wh2, Wl2);
    gru_pre_mfma_kernel<<<760, 256, 0, stream>>>(A, Wh0, Wl0, Wh1, Wl1, Wh2, Wl2,
                                                 part0, part1, part2);
    gru_reduce_fused_kernel<<<1144, 192, 0, stream>>>(part0, part1, part2,
                                                      bih[0], bih[1], bih[2],
                                                      xp0, xp1, xp2);
    gru_scan_kernel<<<12, 192, 0, stream>>>(xp0, xp1, xp2,
                                            Whh[0], Whh[1], Whh[2],
                                            bhh[0], bhh[1], bhh[2], hcat);
    head_kernel<<<1, 512, 0, stream>>>(hcat, W1, b1, W2, b2, out);
}

// Round 8
// 1098.267 us; speedup vs baseline: 4.8513x; 1.3278x over previous
//
#include <hip/hip_runtime.h>
#include <math.h>

#define NN 500
#define DD 64
#define NPAD 512             // adjT padded to [512][512]
#define COLS 65536           // 1024 * 64
#define BS_TOT 1024          // B*S
#define I_DIM 32000          // N*D
#define KS_GRU 40            // K-split for GRU pre-GEMM
#define KSL 800              // 32000/40

typedef __attribute__((ext_vector_type(8))) short bf16x8;
typedef __attribute__((ext_vector_type(4))) float f32x4;

__device__ __forceinline__ float gelu_f(float x) {
    return 0.5f * x * (1.0f + erff(x * 0.70710678118654752440f));
}

__device__ __forceinline__ unsigned short bf16_rn(float x) {
    unsigned int u = __float_as_uint(x);
    unsigned int r = u + 0x7FFFu + ((u >> 16) & 1u);
    return (unsigned short)(r >> 16);
}
__device__ __forceinline__ float bf16_tof(unsigned short h) {
    return __uint_as_float(((unsigned int)h) << 16);
}

__device__ __forceinline__ void split4(float4 v, short4& h4, short4& l4) {
    h4.x = (short)bf16_rn(v.x); l4.x = (short)bf16_rn(v.x - bf16_tof((unsigned short)h4.x));
    h4.y = (short)bf16_rn(v.y); l4.y = (short)bf16_rn(v.y - bf16_tof((unsigned short)h4.y));
    h4.z = (short)bf16_rn(v.z); l4.z = (short)bf16_rn(v.z - bf16_tof((unsigned short)h4.z));
    h4.w = (short)bf16_rn(v.w); l4.w = (short)bf16_rn(v.w - bf16_tof((unsigned short)h4.w));
}

// LDS XOR swizzle (16B granularity within 64B k-extent)
__device__ __forceinline__ int swz_k(int row, int kbyte) {
    return kbyte ^ (((row >> 3) & 3) << 4);
}

// ---------------------------------------------------------------- adjacency
__global__ __launch_bounds__(512)
void adj_kernel(const float* __restrict__ fe, const float* __restrict__ te,
                short* __restrict__ adjTh, short* __restrict__ adjTl)
{
    __shared__ float fr[32];
    __shared__ float red[8];
    __shared__ float red2[8];
    const int n = blockIdx.x;
    const int tid = threadIdx.x;
    if (tid < 32) fr[tid] = fe[n * 32 + tid];
    __syncthreads();
    const int m = tid;
    float s = -1e30f;
    if (m < NN) {
        float acc = 0.f;
        #pragma unroll
        for (int f = 0; f < 32; ++f) acc += fr[f] * te[m * 32 + f];
        s = acc * 2.0f;   // 1/TEMP
    }
    float v = s;
    #pragma unroll
    for (int off = 32; off; off >>= 1) v = fmaxf(v, __shfl_xor(v, off));
    if ((tid & 63) == 0) red[tid >> 6] = v;
    __syncthreads();
    float bmax = red[0];
    #pragma unroll
    for (int i = 1; i < 8; ++i) bmax = fmaxf(bmax, red[i]);
    float e = (m < NN) ? expf(s - bmax) : 0.f;
    float v2 = e;
    #pragma unroll
    for (int off = 32; off; off >>= 1) v2 += __shfl_xor(v2, off);
    if ((tid & 63) == 0) red2[tid >> 6] = v2;
    __syncthreads();
    float bsum = 0.f;
    #pragma unroll
    for (int i = 0; i < 8; ++i) bsum += red2[i];
    if (m < NN) {
        float p = e / bsum;
        unsigned short h = bf16_rn(p);
        adjTh[(size_t)m * NPAD + n] = (short)h;
        adjTl[(size_t)m * NPAD + n] = (short)bf16_rn(p - bf16_tof(h));
    }
}

// ---------------------------------------------------------------- input proj
__global__ __launch_bounds__(256)
void proj_kernel(const float* __restrict__ xin, const float* __restrict__ ipW,
                 const float* __restrict__ ipb, float* __restrict__ Xp)
{
    __shared__ float wT[32][64];   // [f][d]
    __shared__ float xr[16][32];
    const int tid = threadIdx.x;
    const int n = blockIdx.y;
    const int bs0 = blockIdx.x * 16;
    for (int idx = tid; idx < 2048; idx += 256) {
        int d = idx >> 5, f = idx & 31;
        wT[f][d] = ipW[idx];
    }
    if (tid < 128) {
        int r = tid >> 3, fq = tid & 7;
        float4 v = *(const float4*)&xin[((size_t)(bs0 + r) * NN + n) * 32 + fq * 4];
        *(float4*)&xr[r][fq * 4] = v;
    }
    __syncthreads();
    const int lane = tid & 63, wv = tid >> 6;
    #pragma unroll
    for (int q = 0; q < 4; ++q) {
        int r = wv * 4 + q;
        float acc = ipb[lane];
        #pragma unroll
        for (int f = 0; f < 32; ++f) acc += xr[r][f] * wT[f][lane];
        Xp[((size_t)n * BS_TOT + bs0 + r) * 64 + lane] = gelu_f(acc);
    }
}

// ---------------------------------------------------------------- agg GEMM (split-bf16 MFMA)
__global__ __launch_bounds__(256)
void agg_mfma_kernel(const float* __restrict__ Xin,
                     const short* __restrict__ adjTh, const short* __restrict__ adjTl,
                     float* __restrict__ Cout)
{
    __shared__ __align__(16) short Ah[128 * 40];
    __shared__ __align__(16) short Al[128 * 40];
    __shared__ __align__(16) short Bh[128 * 40];
    __shared__ __align__(16) short Bl[128 * 40];

    const int tid  = threadIdx.x;
    const int lane = tid & 63;
    const int wave = tid >> 6;
    const int wm = (wave >> 1) * 64;
    const int wc = (wave & 1) * 64;
    const int q = lane >> 4, r16 = lane & 15;
    const int c0 = blockIdx.x * 128;
    const int m0 = blockIdx.y * 128;

    const int sa_m = tid >> 1, sa_kh = tid & 1;
    const int sb_c = tid & 127, sb_kh = tid >> 7;

    f32x4 acc[4][4];
    #pragma unroll
    for (int i = 0; i < 4; ++i)
        #pragma unroll
        for (int j = 0; j < 4; ++j) acc[i][j] = (f32x4){0.f, 0.f, 0.f, 0.f};

    for (int kc = 0; kc < 16; ++kc) {
        const int k0 = kc * 32;
        // ---- stage A: pre-split bf16, pure copy
        {
            const size_t base = (size_t)(m0 + sa_m) * NPAD + k0 + sa_kh * 16;
            bf16x8 h0 = *(const bf16x8*)&adjTh[base];
            bf16x8 h1 = *(const bf16x8*)&adjTh[base + 8];
            bf16x8 l0 = *(const bf16x8*)&adjTl[base];
            bf16x8 l1 = *(const bf16x8*)&adjTl[base + 8];
            char* rowH = (char*)Ah + sa_m * 80;
            char* rowL = (char*)Al + sa_m * 80;
            *(bf16x8*)(rowH + swz_k(sa_m, sa_kh * 32))      = h0;
            *(bf16x8*)(rowH + swz_k(sa_m, sa_kh * 32 + 16)) = h1;
            *(bf16x8*)(rowL + swz_k(sa_m, sa_kh * 32))      = l0;
            *(bf16x8*)(rowL + swz_k(sa_m, sa_kh * 32 + 16)) = l1;
        }
        // ---- stage B transposed: Bt[c][k] (guard k >= 500 -> 0), fp32 split
        {
            const size_t cb = (size_t)(c0 + sb_c);
            char* rowH = (char*)Bh + sb_c * 80;
            char* rowL = (char*)Bl + sb_c * 80;
            #pragma unroll
            for (int qd = 0; qd < 4; ++qd) {
                float xv[4];
                #pragma unroll
                for (int e = 0; e < 4; ++e) {
                    int kk = k0 + sb_kh * 16 + qd * 4 + e;
                    xv[e] = (kk < NN) ? Xin[(size_t)kk * COLS + cb] : 0.f;
                }
                short4 h4, l4;
                split4(make_float4(xv[0], xv[1], xv[2], xv[3]), h4, l4);
                int kb = swz_k(sb_c, sb_kh * 32 + qd * 8);
                *(short4*)(rowH + kb) = h4;
                *(short4*)(rowL + kb) = l4;
            }
        }
        __syncthreads();
        bf16x8 ah[4], al[4];
        #pragma unroll
        for (int mi = 0; mi < 4; ++mi) {
            int row = wm + mi * 16 + r16;
            int kb = swz_k(row, q * 16);
            ah[mi] = *(const bf16x8*)((const char*)Ah + row * 80 + kb);
            al[mi] = *(const bf16x8*)((const char*)Al + row * 80 + kb);
        }
        #pragma unroll
        for (int ci = 0; ci < 4; ++ci) {
            int row = wc + ci * 16 + r16;
            int kb = swz_k(row, q * 16);
            bf16x8 bh = *(const bf16x8*)((const char*)Bh + row * 80 + kb);
            bf16x8 bl = *(const bf16x8*)((const char*)Bl + row * 80 + kb);
            #pragma unroll
            for (int mi = 0; mi < 4; ++mi) {
                acc[mi][ci] = __builtin_amdgcn_mfma_f32_16x16x32_bf16(ah[mi], bh, acc[mi][ci], 0, 0, 0);
                acc[mi][ci] = __builtin_amdgcn_mfma_f32_16x16x32_bf16(ah[mi], bl, acc[mi][ci], 0, 0, 0);
                acc[mi][ci] = __builtin_amdgcn_mfma_f32_16x16x32_bf16(al[mi], bh, acc[mi][ci], 0, 0, 0);
            }
        }
        __syncthreads();
    }
    #pragma unroll
    for (int mi = 0; mi < 4; ++mi) {
        #pragma unroll
        for (int r = 0; r < 4; ++r) {
            int m = m0 + wm + mi * 16 + q * 4 + r;
            if (m < NN) {
                #pragma unroll
                for (int ci = 0; ci < 4; ++ci) {
                    size_t idx = (size_t)m * COLS + c0 + wc + ci * 16 + r16;
                    Cout[idx] = acc[mi][ci][r] + Xin[idx];
                }
            }
        }
    }
}

// ---------------------------------------------------------------- h + LN (split-bf16 MFMA, in-place)
// rows = n*1024+bs (512000 total); h[row][e] = sum_d X[row][d]*glW[e][d];
// out = LN_e(gelu(h + glb)) * glg + glbe.  128 rows/block, 4 waves x 32 rows.
// LDS row stride 72 shorts (36 words -> 2-way banks, free; no swizzle).
#define HLN_B 144   // row stride in bytes
__global__ __launch_bounds__(256)
void hln_mfma_kernel(float* __restrict__ Xio, const float* __restrict__ glW,
                     const float* __restrict__ glb, const float* __restrict__ glg,
                     const float* __restrict__ glbe)
{
    __shared__ __align__(16) short Ah[128 * 72];
    __shared__ __align__(16) short Al[128 * 72];
    __shared__ __align__(16) short Bh[64 * 72];
    __shared__ __align__(16) short Bl[64 * 72];

    const int tid  = threadIdx.x;
    const int lane = tid & 63;
    const int wave = tid >> 6;
    const int q = lane >> 4, r16 = lane & 15;
    const size_t row0 = (size_t)blockIdx.x * 128;

    // per-lane epilogue params for e = ci*16 + r16
    float bB[4], bG[4], bE[4];
    #pragma unroll
    for (int ci = 0; ci < 4; ++ci) {
        int e = ci * 16 + r16;
        bB[ci] = glb[e]; bG[ci] = glg[e]; bE[ci] = glbe[e];
    }

    // ---- stage B: glW[e][d] -> split bf16 [e][k=d]
    #pragma unroll
    for (int l = 0; l < 4; ++l) {
        int idx = tid + l * 256;       // 1024 float4
        int e = idx >> 4, fq = idx & 15;
        float4 v = *(const float4*)&glW[e * 64 + fq * 4];
        short4 h4, l4;
        split4(v, h4, l4);
        *(short4*)((char*)Bh + e * HLN_B + fq * 8) = h4;
        *(short4*)((char*)Bl + e * HLN_B + fq * 8) = l4;
    }
    // ---- stage A: 128 rows x 64 d fp32 -> split bf16
    #pragma unroll
    for (int l = 0; l < 8; ++l) {
        int idx = tid + l * 256;       // 2048 float4
        int row = idx >> 4, fq = idx & 15;
        float4 v = *(const float4*)&Xio[(row0 + row) * 64 + fq * 4];
        short4 h4, l4;
        split4(v, h4, l4);
        *(short4*)((char*)Ah + row * HLN_B + fq * 8) = h4;
        *(short4*)((char*)Al + row * HLN_B + fq * 8) = l4;
    }
    __syncthreads();

    f32x4 acc[2][4];
    #pragma unroll
    for (int i = 0; i < 2; ++i)
        #pragma unroll
        for (int j = 0; j < 4; ++j) acc[i][j] = (f32x4){0.f, 0.f, 0.f, 0.f};

    #pragma unroll
    for (int ks = 0; ks < 2; ++ks) {
        bf16x8 ah[2], al[2];
        #pragma unroll
        for (int mi = 0; mi < 2; ++mi) {
            int row = wave * 32 + mi * 16 + r16;
            ah[mi] = *(const bf16x8*)((const char*)Ah + row * HLN_B + ks * 64 + q * 16);
            al[mi] = *(const bf16x8*)((const char*)Al + row * HLN_B + ks * 64 + q * 16);
        }
        #pragma unroll
        for (int ci = 0; ci < 4; ++ci) {
            int e = ci * 16 + r16;
            bf16x8 bh = *(const bf16x8*)((const char*)Bh + e * HLN_B + ks * 64 + q * 16);
            bf16x8 bl = *(const bf16x8*)((const char*)Bl + e * HLN_B + ks * 64 + q * 16);
            #pragma unroll
            for (int mi = 0; mi < 2; ++mi) {
                acc[mi][ci] = __builtin_amdgcn_mfma_f32_16x16x32_bf16(ah[mi], bh, acc[mi][ci], 0, 0, 0);
                acc[mi][ci] = __builtin_amdgcn_mfma_f32_16x16x32_bf16(ah[mi], bl, acc[mi][ci], 0, 0, 0);
                acc[mi][ci] = __builtin_amdgcn_mfma_f32_16x16x32_bf16(al[mi], bh, acc[mi][ci], 0, 0, 0);
            }
        }
    }

    // ---- epilogue: GELU + LN per row; lane holds e = ci*16+r16 for rows q*4+r
    #pragma unroll
    for (int mi = 0; mi < 2; ++mi) {
        #pragma unroll
        for (int r = 0; r < 4; ++r) {
            float h[4];
            float s1 = 0.f;
            #pragma unroll
            for (int ci = 0; ci < 4; ++ci) {
                h[ci] = gelu_f(acc[mi][ci][r] + bB[ci]);
                s1 += h[ci];
            }
            #pragma unroll
            for (int off = 1; off < 16; off <<= 1) s1 += __shfl_xor(s1, off);
            float mu = s1 * (1.f / 64.f);
            float s2 = 0.f;
            #pragma unroll
            for (int ci = 0; ci < 4; ++ci) { float dc = h[ci] - mu; s2 += dc * dc; }
            #pragma unroll
            for (int off = 1; off < 16; off <<= 1) s2 += __shfl_xor(s2, off);
            float rs = 1.f / sqrtf(s2 * (1.f / 64.f) + 1e-5f);
            size_t grow = row0 + wave * 32 + mi * 16 + q * 4 + r;
            #pragma unroll
            for (int ci = 0; ci < 4; ++ci)
                Xio[grow * 64 + ci * 16 + r16] = (h[ci] - mu) * rs * bG[ci] + bE[ci];
        }
    }
}

// ---------------------------------------------------------------- Wih split-convert
__global__ __launch_bounds__(256)
void wconv_kernel(const float* __restrict__ W0, const float* __restrict__ W1,
                  const float* __restrict__ W2,
                  short* __restrict__ h0, short* __restrict__ l0,
                  short* __restrict__ h1, short* __restrict__ l1,
                  short* __restrict__ h2, short* __restrict__ l2)
{
    const int gi = blockIdx.y;
    const float* W = (gi == 0) ? W0 : (gi == 1) ? W1 : W2;
    short* H = (gi == 0) ? h0 : (gi == 1) ? h1 : h2;
    short* L = (gi == 0) ? l0 : (gi == 1) ? l1 : l2;
    const size_t i = ((size_t)blockIdx.x * 256 + threadIdx.x) * 4;
    float4 v = *(const float4*)&W[i];
    short4 h4, l4;
    split4(v, h4, l4);
    *(short4*)&H[i] = h4;
    *(short4*)&L[i] = l4;
}

// ---------------------------------------------------------------- GRU pre-GEMM (MFMA)
__global__ __launch_bounds__(256)
void gru_pre_mfma_kernel(const float* __restrict__ Xp,
                         const short* __restrict__ Wh0, const short* __restrict__ Wl0,
                         const short* __restrict__ Wh1, const short* __restrict__ Wl1,
                         const short* __restrict__ Wh2, const short* __restrict__ Wl2,
                         float* __restrict__ p0, float* __restrict__ p1,
                         float* __restrict__ p2)
{
    __shared__ __align__(16) short Ah[64 * 40];
    __shared__ __align__(16) short Al[64 * 40];
    __shared__ __align__(16) short Bh[192 * 40];
    __shared__ __align__(16) short Bl[192 * 40];

    const int bid = blockIdx.x;
    int gi, mtid, ks;
    if (bid < 40)       { gi = 0; mtid = 0;             ks = bid; }
    else if (bid < 120) { int r = bid - 40;  gi = 1; mtid = r & 1;  ks = r >> 1; }
    else                { int r = bid - 120; gi = 2; mtid = r & 15; ks = r >> 4; }
    const short* Wh = (gi == 0) ? Wh0 : (gi == 1) ? Wh1 : Wh2;
    const short* Wl = (gi == 0) ? Wl0 : (gi == 1) ? Wl1 : Wl2;
    float* partial  = (gi == 0) ? p0 : (gi == 1) ? p1 : p2;
    const int Trows = (gi == 0) ? 10 : (gi == 1) ? 20 : 256;
    const int toff  = (gi == 0) ? 246 : (gi == 1) ? 236 : 0;
    const int M     = (gi == 0) ? 40 : (gi == 1) ? 80 : 1024;
    const int R0 = mtid * 64;

    const int tid  = threadIdx.x;
    const int lane = tid & 63;
    const int wave = tid >> 6;
    const int wr = (wave & 1) * 32;
    const int wg = (wave >> 1) * 96;
    const int q = lane >> 4, r16 = lane & 15;

    const int sa_r = tid >> 2, sa_kq = tid & 3;
    const bool vldA = (R0 + sa_r < M);
    int btA = 0;
    if (vldA) { int R = R0 + sa_r; int b = R / Trows, t = R - b * Trows; btA = b * 256 + toff + t; }

    f32x4 acc[2][6];
    #pragma unroll
    for (int i = 0; i < 2; ++i)
        #pragma unroll
        for (int j = 0; j < 6; ++j) acc[i][j] = (f32x4){0.f, 0.f, 0.f, 0.f};

    for (int c = 0; c < KSL / 32; ++c) {
        const int k0 = ks * KSL + c * 32;
        {
            const int kk = k0 + sa_kq * 8;
            const int nn = kk >> 6, d0 = kk & 63;
            float4 v0 = make_float4(0.f, 0.f, 0.f, 0.f), v1 = v0;
            if (vldA) {
                const float* src = &Xp[((size_t)nn * BS_TOT + btA) * 64 + d0];
                v0 = *(const float4*)src;
                v1 = *(const float4*)(src + 4);
            }
            short4 h0, l0, h1, l1;
            split4(v0, h0, l0);
            split4(v1, h1, l1);
            int kb = swz_k(sa_r, sa_kq * 16);
            char* rowH = (char*)Ah + sa_r * 80;
            char* rowL = (char*)Al + sa_r * 80;
            *(short4*)(rowH + kb) = h0; *(short4*)(rowH + kb + 8) = h1;
            *(short4*)(rowL + kb) = l0; *(short4*)(rowL + kb + 8) = l1;
        }
        #pragma unroll
        for (int l = 0; l < 3; ++l) {
            int idx = tid + l * 256;
            int g = idx >> 2, kq = idx & 3;
            const size_t src = (size_t)g * I_DIM + k0 + kq * 8;
            bf16x8 hv = *(const bf16x8*)&Wh[src];
            bf16x8 lv = *(const bf16x8*)&Wl[src];
            int kb = swz_k(g, kq * 16);
            *(bf16x8*)((char*)Bh + g * 80 + kb) = hv;
            *(bf16x8*)((char*)Bl + g * 80 + kb) = lv;
        }
        __syncthreads();
        bf16x8 ah[2], al[2];
        #pragma unroll
        for (int mi = 0; mi < 2; ++mi) {
            int row = wr + mi * 16 + r16;
            int kb = swz_k(row, q * 16);
            ah[mi] = *(const bf16x8*)((const char*)Ah + row * 80 + kb);
            al[mi] = *(const bf16x8*)((const char*)Al + row * 80 + kb);
        }
        #pragma unroll
        for (int ci = 0; ci < 6; ++ci) {
            int grow = wg + ci * 16 + r16;
            int kb = swz_k(grow, q * 16);
            bf16x8 bh = *(const bf16x8*)((const char*)Bh + grow * 80 + kb);
            bf16x8 bl = *(const bf16x8*)((const char*)Bl + grow * 80 + kb);
            #pragma unroll
            for (int mi = 0; mi < 2; ++mi) {
                acc[mi][ci] = __builtin_amdgcn_mfma_f32_16x16x32_bf16(ah[mi], bh, acc[mi][ci], 0, 0, 0);
                acc[mi][ci] = __builtin_amdgcn_mfma_f32_16x16x32_bf16(ah[mi], bl, acc[mi][ci], 0, 0, 0);
                acc[mi][ci] = __builtin_amdgcn_mfma_f32_16x16x32_bf16(al[mi], bh, acc[mi][ci], 0, 0, 0);
            }
        }
        __syncthreads();
    }
    #pragma unroll
    for (int mi = 0; mi < 2; ++mi) {
        #pragma unroll
        for (int r = 0; r < 4; ++r) {
            int R = R0 + wr + mi * 16 + q * 4 + r;
            if (R < M) {
                #pragma unroll
                for (int ci = 0; ci < 6; ++ci)
                    partial[((size_t)ks * M + R) * 192 + wg + ci * 16 + r16] = acc[mi][ci][r];
            }
        }
    }
}

// ---------------------------------------------------------------- reduce (all 3 fused)
__global__ __launch_bounds__(192)
void gru_reduce_fused_kernel(const float* __restrict__ p0, const float* __restrict__ p1,
                             const float* __restrict__ p2,
                             const float* __restrict__ bih0, const float* __restrict__ bih1,
                             const float* __restrict__ bih2,
                             float* __restrict__ xp0, float* __restrict__ xp1,
                             float* __restrict__ xp2)
{
    int r = blockIdx.x;
    const float* partial; const float* bih; float* xp; int M;
    if (r < 40)       { partial = p0; bih = bih0; xp = xp0; M = 40; }
    else if (r < 120) { r -= 40;  partial = p1; bih = bih1; xp = xp1; M = 80; }
    else              { r -= 120; partial = p2; bih = bih2; xp = xp2; M = 1024; }
    const int g = threadIdx.x;
    float acc = bih[g];
    for (int ks = 0; ks < KS_GRU; ++ks)
        acc += partial[((size_t)ks * M + r) * 192 + g];
    xp[(size_t)r * 192 + g] = acc;
}

// ---------------------------------------------------------------- GRU scan
__global__ __launch_bounds__(192)
void gru_scan_kernel(const float* __restrict__ xp_s, const float* __restrict__ xp_m,
                     const float* __restrict__ xp_l,
                     const float* __restrict__ Whh_s, const float* __restrict__ Whh_m,
                     const float* __restrict__ Whh_l,
                     const float* __restrict__ bhh_s, const float* __restrict__ bhh_m,
                     const float* __restrict__ bhh_l,
                     float* __restrict__ hcat)
{
    __shared__ float h[64];
    __shared__ float gh[192];
    const int blk = blockIdx.x;
    const int g3 = blk >> 2, b = blk & 3;
    const float* xp  = (g3 == 0) ? xp_s : (g3 == 1) ? xp_m : xp_l;
    const float* Whh = (g3 == 0) ? Whh_s : (g3 == 1) ? Whh_m : Whh_l;
    const float* bhh = (g3 == 0) ? bhh_s : (g3 == 1) ? bhh_m : bhh_l;
    const int T = (g3 == 0) ? 10 : (g3 == 1) ? 20 : 256;
    const int g = threadIdx.x;

    float w[64];
    #pragma unroll
    for (int k4 = 0; k4 < 16; ++k4) {
        float4 v = *(const float4*)&Whh[g * 64 + k4 * 4];
        w[k4 * 4 + 0] = v.x; w[k4 * 4 + 1] = v.y;
        w[k4 * 4 + 2] = v.z; w[k4 * 4 + 3] = v.w;
    }
    const float bh = bhh[g];
    if (g < 64) h[g] = 0.f;

    const float* xpb = xp + (size_t)b * T * 192;
    float xr_c = 0.f, xz_c = 0.f, xn_c = 0.f;
    if (g < 64) { xr_c = xpb[g]; xz_c = xpb[64 + g]; xn_c = xpb[128 + g]; }
    __syncthreads();

    for (int t = 0; t < T; ++t) {
        float xr_n = 0.f, xz_n = 0.f, xn_n = 0.f;
        if (t + 1 < T && g < 64) {
            const float* xq = xpb + (size_t)(t + 1) * 192;
            xr_n = xq[g]; xz_n = xq[64 + g]; xn_n = xq[128 + g];
        }
        float a0 = 0.f, a1 = 0.f, a2 = 0.f, a3 = 0.f;
        #pragma unroll
        for (int k4 = 0; k4 < 16; ++k4) {
            float4 hv = ((const float4*)h)[k4];
            a0 += hv.x * w[k4 * 4 + 0];
            a1 += hv.y * w[k4 * 4 + 1];
            a2 += hv.z * w[k4 * 4 + 2];
            a3 += hv.w * w[k4 * 4 + 3];
        }
        gh[g] = bh + ((a0 + a1) + (a2 + a3));
        __syncthreads();
        if (g < 64) {
            float hr = gh[g], hz = gh[64 + g], hn = gh[128 + g];
            float r = 1.f / (1.f + __expf(-(xr_c + hr)));
            float z = 1.f / (1.f + __expf(-(xz_c + hz)));
            float pre = xn_c + r * hn;
            float e2 = __expf(2.f * pre);
            float nv = 1.f - 2.f / (e2 + 1.f);   // tanh
            h[g] = (1.f - z) * nv + z * h[g];
        }
        __syncthreads();
        xr_c = xr_n; xz_c = xz_n; xn_c = xn_n;
    }
    if (g < 64) hcat[b * 192 + g3 * 64 + g] = h[g];
}

// ---------------------------------------------------------------- head
__global__ __launch_bounds__(512)
void head_kernel(const float* __restrict__ hcat,
                 const float* __restrict__ W1, const float* __restrict__ b1,
                 const float* __restrict__ W2, const float* __restrict__ b2,
                 float* __restrict__ out)
{
    __shared__ float hc[4][192];
    __shared__ float h1[4][64];
    const int tid = threadIdx.x;
    for (int i = tid; i < 768; i += 512) hc[i / 192][i % 192] = hcat[i];
    __syncthreads();
    if (tid < 256) {
        int b = tid >> 6, e = tid & 63;
        float acc = b1[e];
        #pragma unroll
        for (int k = 0; k < 192; ++k) acc += hc[b][k] * W1[e * 192 + k];
        h1[b][e] = gelu_f(acc);
    }
    __syncthreads();
    for (int o = tid; o < 2000; o += 512) {
        int b = o / 500, n = o % 500;
        float acc = b2[n];
        #pragma unroll
        for (int k = 0; k < 64; ++k) acc += h1[b][k] * W2[n * 64 + k];
        out[o] = acc;
    }
}

// ================================================================ launch
extern "C" void kernel_launch(void* const* d_in, const int* in_sizes, int n_in,
                              void* d_out, int out_size, void* d_ws, size_t ws_size,
                              hipStream_t stream)
{
    (void)in_sizes; (void)n_in; (void)out_size; (void)ws_size;
    const float* x    = (const float*)d_in[0];
    const float* ipW  = (const float*)d_in[1];
    const float* ipb  = (const float*)d_in[2];
    const float* fe   = (const float*)d_in[3];
    const float* te   = (const float*)d_in[4];
    const float* glW  = (const float*)d_in[5];
    const float* glb  = (const float*)d_in[6];
    const float* glg  = (const float*)d_in[7];
    const float* glbe = (const float*)d_in[8];
    const float* Wih[3] = {(const float*)d_in[9],  (const float*)d_in[13], (const float*)d_in[17]};
    const float* Whh[3] = {(const float*)d_in[10], (const float*)d_in[14], (const float*)d_in[18]};
    const float* bih[3] = {(const float*)d_in[11], (const float*)d_in[15], (const float*)d_in[19]};
    const float* bhh[3] = {(const float*)d_in[12], (const float*)d_in[16], (const float*)d_in[20]};
    const float* W1 = (const float*)d_in[21];
    const float* b1 = (const float*)d_in[22];
    const float* W2 = (const float*)d_in[23];
    const float* b2 = (const float*)d_in[24];
    float* out = (float*)d_out;

    float* ws   = (float*)d_ws;
    float* A    = ws;                  // 32,768,000 floats (500*65536)  X ping
    float* Bb   = A + 32768000;        // 32,768,000 floats             X pong
    short* adjTh = (short*)(Bb + 32768000);    // 512*512 shorts
    short* adjTl = adjTh + NPAD * NPAD;        // 512*512 shorts
    // GRU-phase scratch overlays Bb (dead after layer-2 GEMM):
    short* wbase = (short*)Bb;
    short* Wh0 = wbase;                        // 6,144,000 shorts each
    short* Wl0 = Wh0 + 6144000;
    short* Wh1 = Wl0 + 6144000;
    short* Wl1 = Wh1 + 6144000;
    short* Wh2 = Wl1 + 6144000;
    short* Wl2 = Wh2 + 6144000;
    float* pbase = Bb + 18432000;
    float* part0 = pbase;                      // 40*40*192   = 307,200
    float* part1 = part0 + 307200;             // 40*80*192   = 614,400
    float* part2 = part1 + 614400;             // 40*1024*192 = 7,864,320
    float* xp0   = part2 + 7864320;            // 7,680
    float* xp1   = xp0 + 7680;                 // 15,360
    float* xp2   = xp1 + 15360;                // 196,608
    float* hcat  = xp2 + 196608;               // 768

    hipMemsetAsync(adjTh, 0, (size_t)NPAD * NPAD * 2 * sizeof(short), stream);
    adj_kernel<<<NN, 512, 0, stream>>>(fe, te, adjTh, adjTl);
    proj_kernel<<<dim3(64, NN), 256, 0, stream>>>(x, ipW, ipb, A);

    // layer 1: A -> Bb (agg+residual), then h+LN in-place on Bb
    agg_mfma_kernel<<<dim3(512, 4), 256, 0, stream>>>(A, adjTh, adjTl, Bb);
    hln_mfma_kernel<<<4000, 256, 0, stream>>>(Bb, glW, glb, glg, glbe);
    // layer 2: Bb -> A, then in-place on A
    agg_mfma_kernel<<<dim3(512, 4), 256, 0, stream>>>(Bb, adjTh, adjTl, A);
    hln_mfma_kernel<<<4000, 256, 0, stream>>>(A, glW + 4096, glb + 64, glg + 64, glbe + 64);

    wconv_kernel<<<dim3(6000, 3), 256, 0, stream>>>(Wih[0], Wih[1], Wih[2],
                                                    Wh0, Wl0, Wh1, Wl1, Wh2, Wl2);
    gru_pre_mfma_kernel<<<760, 256, 0, stream>>>(A, Wh0, Wl0, Wh1, Wl1, Wh2, Wl2,
                                                 part0, part1, part2);
    gru_reduce_fused_kernel<<<1144, 192, 0, stream>>>(part0, part1, part2,
                                                      bih[0], bih[1], bih[2],
                                                      xp0, xp1, xp2);
    gru_scan_kernel<<<12, 192, 0, stream>>>(xp0, xp1, xp2,
                                            Whh[0], Whh[1], Whh[2],
                                            bhh[0], bhh[1], bhh[2], hcat);
    head_kernel<<<1, 512, 0, stream>>>(hcat, W1, b1, W2, b2, out);
}